// Round 4
// baseline (1063.660 us; speedup 1.0000x reference)
//
#include <hip/hip_runtime.h>
#include <hip/hip_bf16.h>

#define H_ 16
#define KVH_ 4
#define D_ 128
#define L_ 2048
#define B_ 2
#define HID_ 2048
#define WIN_ 1024
#define NS_ 8

typedef __attribute__((ext_vector_type(8))) short short8;
typedef __attribute__((ext_vector_type(4))) float floatx4;

__device__ inline float bf16_to_f(unsigned short u) {
    union { unsigned int i; float f; } c; c.i = ((unsigned int)u) << 16; return c.f;
}
__device__ inline unsigned short f_to_bf16(float f) {
    __hip_bfloat16 h = __float2bfloat16(f);
    return *(unsigned short*)&h;
}

// ---------------------------------------------------------------------------
// Kernel 0: runtime dtype detection (belt-and-braces; expected: fp32 + int64).
// flags[0]=1 if float tensors are bf16, 0 if fp32. Test: u16[2i] of
//   hidden_states. bf16 world -> bf16 of N(0,1), exp field <= 130 unless
//   |x|>=8 (P~1e-15). fp32 world -> low mantissa word, uniform bits,
//   P(all 32 have exp<=130) ~ 5e-10.
// flags[1] = int stride in i32 words (1=int32, 2=int64). position_ids is a
//   tiled arange: pids_i32[1] == 1 (int32) or 0 (int64 high word of 0).
// ---------------------------------------------------------------------------
__global__ void detect_kernel(const unsigned short* __restrict__ hs_u,
                              const int* __restrict__ pids,
                              int* __restrict__ flags) {
    if (threadIdx.x == 0 && blockIdx.x == 0) {
        int isbf = 1;
        for (int i = 0; i < 32; i++) {
            unsigned short u = hs_u[2 * i];
            int e = (u >> 7) & 0xFF;
            if (e > 130) isbf = 0;
        }
        flags[0] = isbf;
        flags[1] = (pids[1] == 0) ? 2 : 1;
    }
}

// ---------------------------------------------------------------------------
// Kernel 1: per-batch rank scan + inverse poslist (Hillis-Steele over 8-state
// count vectors; cross-validated against a sequential version in r3).
// rank[b][l] = #(l' < l, sid=sid[l]); poslist[b][s][rank] = l
// ---------------------------------------------------------------------------
__global__ __launch_bounds__(256) void scan_kernel(const int* __restrict__ sid,
                                                   int* __restrict__ rank,
                                                   int* __restrict__ poslist,
                                                   const int* __restrict__ flags) {
    int stride = flags[1];
    int b = blockIdx.x;
    int t = threadIdx.x;
    __shared__ int cnt[256][NS_];
    __shared__ int pre[256][NS_];
    const int* s = sid + (size_t)b * L_ * stride;
    int myid[8];
#pragma unroll
    for (int i = 0; i < 8; i++) myid[i] = s[(t * 8 + i) * stride];
#pragma unroll
    for (int st = 0; st < NS_; st++) cnt[t][st] = 0;
#pragma unroll
    for (int i = 0; i < 8; i++) cnt[t][myid[i]]++;
    __syncthreads();
    for (int off = 1; off < 256; off <<= 1) {
        int add[NS_];
        if (t >= off)
#pragma unroll
            for (int st = 0; st < NS_; st++) add[st] = cnt[t - off][st];
        __syncthreads();
        if (t >= off)
#pragma unroll
            for (int st = 0; st < NS_; st++) cnt[t][st] += add[st];
        __syncthreads();
    }
#pragma unroll
    for (int st = 0; st < NS_; st++) pre[t][st] = t ? cnt[t - 1][st] : 0;
    __syncthreads();
#pragma unroll
    for (int i = 0; i < 8; i++) {
        int sd = myid[i];
        int r = pre[t][sd]++;
        int pos = t * 8 + i;
        rank[b * L_ + pos] = r;
        poslist[((size_t)b * NS_ + sd) * L_ + r] = pos;
    }
}

// ---------------------------------------------------------------------------
// Kernel 2: MFMA bf16 GEMM  C[M,N] = A[M,K] @ B[N,K]^T.
// fp32->bf16 conversion fused into LDS staging (world-dependent).
// c_mode: 0 = C always bf16 (intermediates); 1 = C follows world
// (fp32 store when inputs are fp32 — the harness-visible output).
// a_force_bf: A is always bf16 (o_b) regardless of world.
// ---------------------------------------------------------------------------
__global__ __launch_bounds__(256) void gemm_bt(const void* __restrict__ A,
                                               const void* __restrict__ B,
                                               void* __restrict__ C,
                                               int M, int N, int K,
                                               const int* __restrict__ flags,
                                               int a_force_bf, int c_mode) {
    __shared__ short As[64][40];
    __shared__ short Bs[64][40];
    int tid  = threadIdx.x;
    int wave = tid >> 6, lane = tid & 63;
    int quad = lane >> 4, l16 = lane & 15;
    int bm = blockIdx.y * 64, bn = blockIdx.x * 64;
    int srow = tid >> 2;            // 0..63
    int schunk = (tid & 3) * 8;     // 0,8,16,24
    int world_bf = flags[0];
    int abf = a_force_bf ? 1 : world_bf;

    floatx4 acc[2][2] = {};
    int wm = (wave >> 1) * 32;
    int wn = (wave & 1) * 32;

    for (int k0 = 0; k0 < K; k0 += 32) {
        if (abf) {
            *(short8*)&As[srow][schunk] =
                *(const short8*)((const unsigned short*)A + (size_t)(bm + srow) * K + k0 + schunk);
        } else {
            const float* Af = (const float*)A + (size_t)(bm + srow) * K + k0 + schunk;
            float4 f0 = *(const float4*)Af;
            float4 f1 = *(const float4*)(Af + 4);
            short* d = &As[srow][schunk];
            d[0] = (short)f_to_bf16(f0.x); d[1] = (short)f_to_bf16(f0.y);
            d[2] = (short)f_to_bf16(f0.z); d[3] = (short)f_to_bf16(f0.w);
            d[4] = (short)f_to_bf16(f1.x); d[5] = (short)f_to_bf16(f1.y);
            d[6] = (short)f_to_bf16(f1.z); d[7] = (short)f_to_bf16(f1.w);
        }
        if (world_bf) {
            *(short8*)&Bs[srow][schunk] =
                *(const short8*)((const unsigned short*)B + (size_t)(bn + srow) * K + k0 + schunk);
        } else {
            const float* Bf = (const float*)B + (size_t)(bn + srow) * K + k0 + schunk;
            float4 f0 = *(const float4*)Bf;
            float4 f1 = *(const float4*)(Bf + 4);
            short* d = &Bs[srow][schunk];
            d[0] = (short)f_to_bf16(f0.x); d[1] = (short)f_to_bf16(f0.y);
            d[2] = (short)f_to_bf16(f0.z); d[3] = (short)f_to_bf16(f0.w);
            d[4] = (short)f_to_bf16(f1.x); d[5] = (short)f_to_bf16(f1.y);
            d[6] = (short)f_to_bf16(f1.z); d[7] = (short)f_to_bf16(f1.w);
        }
        __syncthreads();
        short8 a0 = *(const short8*)&As[wm + l16][quad * 8];
        short8 a1 = *(const short8*)&As[wm + 16 + l16][quad * 8];
        short8 b0 = *(const short8*)&Bs[wn + l16][quad * 8];
        short8 b1 = *(const short8*)&Bs[wn + 16 + l16][quad * 8];
        acc[0][0] = __builtin_amdgcn_mfma_f32_16x16x32_bf16(a0, b0, acc[0][0], 0, 0, 0);
        acc[0][1] = __builtin_amdgcn_mfma_f32_16x16x32_bf16(a0, b1, acc[0][1], 0, 0, 0);
        acc[1][0] = __builtin_amdgcn_mfma_f32_16x16x32_bf16(a1, b0, acc[1][0], 0, 0, 0);
        acc[1][1] = __builtin_amdgcn_mfma_f32_16x16x32_bf16(a1, b1, acc[1][1], 0, 0, 0);
        __syncthreads();
    }
    int cf32 = (c_mode == 1) && !world_bf;   // harness output is fp32 in fp32 world
    // C/D layout: col = lane&15, row = (lane>>4)*4 + reg   [m89/m91 verified]
#pragma unroll
    for (int mt = 0; mt < 2; mt++)
#pragma unroll
        for (int nt = 0; nt < 2; nt++)
#pragma unroll
            for (int r = 0; r < 4; r++) {
                int row = bm + wm + mt * 16 + quad * 4 + r;
                int col = bn + wn + nt * 16 + l16;
                size_t idx = (size_t)row * N + col;
                if (cf32) ((float*)C)[idx] = acc[mt][nt][r];
                else      ((unsigned short*)C)[idx] = f_to_bf16(acc[mt][nt][r]);
            }
}

// ---------------------------------------------------------------------------
// Kernel 3: RoPE in place on bf16 q [BL,16,128] and k [BL,4,128]
// pair (i,i+64): q'[i]=q[i]*c - q[i+64]*s ; q'[i+64]=q[i+64]*c + q[i]*s
// ---------------------------------------------------------------------------
__global__ __launch_bounds__(256) void rope_kernel(unsigned short* __restrict__ q,
                                                   unsigned short* __restrict__ k,
                                                   const int* __restrict__ pos_ids,
                                                   const int* __restrict__ flags) {
    int stride = flags[1];
    int idx = blockIdx.x * 256 + threadIdx.x;
    int i = idx & 63;
    int tmp = idx >> 6;
    int head = tmp % 20;
    int bl = tmp / 20;
    if (bl >= B_ * L_) return;
    float posf = (float)pos_ids[bl * stride];
    float inv = exp2f(-(float)i * (2.0f / 128.0f) * 13.287712379549449f);  // 10000^(-2i/128)
    float ang = posf * inv;
    float c = cosf(ang), sn = sinf(ang);
    unsigned short* p = (head < H_) ? (q + ((size_t)bl * H_ + head) * D_)
                                    : (k + ((size_t)bl * KVH_ + (head - H_)) * D_);
    float x0 = bf16_to_f(p[i]), x1 = bf16_to_f(p[i + 64]);
    p[i]      = f_to_bf16(x0 * c - x1 * sn);
    p[i + 64] = f_to_bf16(x1 * c + x0 * sn);
}

// ---------------------------------------------------------------------------
// Kernel 4: attention — one wave per (b,l,h); keys via poslist ranks
// [max(0, r-WIN) .. r] (same-state & causal & window); online softmax fp32.
// ---------------------------------------------------------------------------
__global__ __launch_bounds__(256) void attn_kernel(const unsigned short* __restrict__ q,
                                                   const unsigned short* __restrict__ k,
                                                   const unsigned short* __restrict__ v,
                                                   const int* __restrict__ sid,
                                                   const int* __restrict__ rank,
                                                   const int* __restrict__ poslist,
                                                   unsigned short* __restrict__ o,
                                                   const int* __restrict__ flags) {
    int stride = flags[1];
    int wid = blockIdx.x * 4 + (threadIdx.x >> 6);
    int lane = threadIdx.x & 63;
    int h = wid & (H_ - 1);
    int bl = wid >> 4;
    int b = bl >> 11;                 // L = 2048
    int s = sid[bl * stride];
    int r = rank[bl];
    int lo = max(0, r - WIN_);
    const int* plist = poslist + ((size_t)b * NS_ + s) * L_;
    ushort2 qu = *(const ushort2*)(q + ((size_t)bl * H_ + h) * D_ + lane * 2);
    float q0 = bf16_to_f(qu.x), q1 = bf16_to_f(qu.y);
    int kvh = h >> 2;                 // repeat_interleave: head h -> kv head h/4
    float m = -1e30f, lsum = 0.f, o0 = 0.f, o1 = 0.f;
    const float scale = 0.08838834764831845f;  // 1/sqrt(128)
    for (int j = lo; j <= r; j++) {
        int kpos = plist[j];
        size_t kb = (((size_t)(b << 11) + kpos) * KVH_ + kvh) * D_ + lane * 2;
        ushort2 kf = *(const ushort2*)(k + kb);
        float d = q0 * bf16_to_f(kf.x) + q1 * bf16_to_f(kf.y);
#pragma unroll
        for (int off = 32; off > 0; off >>= 1) d += __shfl_xor(d, off, 64);
        d *= scale;
        float nm = fmaxf(m, d);
        float sc = __expf(m - nm);
        float p = __expf(d - nm);
        ushort2 vf = *(const ushort2*)(v + kb);
        lsum = lsum * sc + p;
        o0 = o0 * sc + p * bf16_to_f(vf.x);
        o1 = o1 * sc + p * bf16_to_f(vf.y);
        m = nm;
    }
    float inv = 1.f / lsum;
    size_t ob = ((size_t)bl * H_ + h) * D_ + lane * 2;
    o[ob]     = f_to_bf16(o0 * inv);
    o[ob + 1] = f_to_bf16(o1 * inv);
}

// ---------------------------------------------------------------------------
extern "C" void kernel_launch(void* const* d_in, const int* in_sizes, int n_in,
                              void* d_out, int out_size, void* d_ws, size_t ws_size,
                              hipStream_t stream) {
    const void* hs = d_in[0];          // [B,L,HID]   fp32 (or bf16)
    const void* Wq = d_in[1];          // [2048,2048]
    const void* Wk = d_in[2];          // [512,2048]
    const void* Wv = d_in[3];          // [512,2048]
    const void* Wo = d_in[4];          // [2048,2048]
    const int* sid  = (const int*)d_in[5];
    const int* pids = (const int*)d_in[6];

    const int M = B_ * L_;  // 4096
    char* w = (char*)d_ws;
    int* flags           = (int*)w;                             //       256 B
    unsigned short* q_b  = (unsigned short*)(w + 256);          // 16,777,216
    unsigned short* k_b  = (unsigned short*)(w + 16777472);     //  4,194,304
    unsigned short* v_b  = (unsigned short*)(w + 20971776);     //  4,194,304
    unsigned short* o_b  = (unsigned short*)(w + 25166080);     // 16,777,216
    int* rank            = (int*)(w + 41943296);                //     16,384
    int* plist           = (int*)(w + 41959680);                //    131,072
    // total ~42.1 MB

    // 0. detect dtypes
    detect_kernel<<<1, 64, 0, stream>>>((const unsigned short*)hs, pids, flags);

    // 1. rank / poslist
    scan_kernel<<<B_, 256, 0, stream>>>(sid, rank, plist, flags);

    // 2. projections (fp32->bf16 fused into staging; bf16 intermediates)
    gemm_bt<<<dim3(HID_ / 64, M / 64), 256, 0, stream>>>(hs, Wq, q_b, M, H_ * D_, HID_, flags, 0, 0);
    gemm_bt<<<dim3((KVH_ * D_) / 64, M / 64), 256, 0, stream>>>(hs, Wk, k_b, M, KVH_ * D_, HID_, flags, 0, 0);
    gemm_bt<<<dim3((KVH_ * D_) / 64, M / 64), 256, 0, stream>>>(hs, Wv, v_b, M, KVH_ * D_, HID_, flags, 0, 0);

    // 3. RoPE
    int rope_threads = M * (H_ + KVH_) * 64;
    rope_kernel<<<(rope_threads + 255) / 256, 256, 0, stream>>>(q_b, k_b, pids, flags);

    // 4. attention
    attn_kernel<<<(M * H_) / 4, 256, 0, stream>>>(q_b, k_b, v_b, sid, rank, plist, o_b, flags);

    // 5. output projection — C follows world dtype (fp32 store in fp32 world)
    gemm_bt<<<dim3(HID_ / 64, M / 64), 256, 0, stream>>>(o_b, Wo, d_out, M, HID_, HID_, flags, 1, 1);
}

// Round 5
// 544.473 us; speedup vs baseline: 1.9536x; 1.9536x over previous
//
#include <hip/hip_runtime.h>
#include <hip/hip_bf16.h>

#define H_ 16
#define KVH_ 4
#define D_ 128
#define L_ 2048
#define B_ 2
#define HID_ 2048
#define WIN_ 1024
#define NS_ 8

typedef __attribute__((ext_vector_type(8))) short short8;
typedef __attribute__((ext_vector_type(4))) float floatx4;

__device__ inline float bf16_to_f(unsigned short u) {
    union { unsigned int i; float f; } c; c.i = ((unsigned int)u) << 16; return c.f;
}
__device__ inline unsigned short f_to_bf16(float f) {
    __hip_bfloat16 h = __float2bfloat16(f);
    return *(unsigned short*)&h;
}

// ---------------------------------------------------------------------------
// Kernel 0: runtime dtype detection (fp32+int64 expected; bf16/int32 safe).
// ---------------------------------------------------------------------------
__global__ void detect_kernel(const unsigned short* __restrict__ hs_u,
                              const int* __restrict__ pids,
                              int* __restrict__ flags) {
    if (threadIdx.x == 0 && blockIdx.x == 0) {
        int isbf = 1;
        for (int i = 0; i < 32; i++) {
            unsigned short u = hs_u[2 * i];
            int e = (u >> 7) & 0xFF;
            if (e > 130) isbf = 0;
        }
        flags[0] = isbf;
        flags[1] = (pids[1] == 0) ? 2 : 1;
    }
}

// ---------------------------------------------------------------------------
// Kernel 1: per-batch rank scan + inverse poslist + per-state counts.
// ---------------------------------------------------------------------------
__global__ __launch_bounds__(256) void scan_kernel(const int* __restrict__ sid,
                                                   int* __restrict__ rank,
                                                   int* __restrict__ poslist,
                                                   int* __restrict__ counts,
                                                   const int* __restrict__ flags) {
    int stride = flags[1];
    int b = blockIdx.x;
    int t = threadIdx.x;
    __shared__ int cnt[256][NS_];
    __shared__ int pre[256][NS_];
    const int* s = sid + (size_t)b * L_ * stride;
    int myid[8];
#pragma unroll
    for (int i = 0; i < 8; i++) myid[i] = s[(t * 8 + i) * stride];
#pragma unroll
    for (int st = 0; st < NS_; st++) cnt[t][st] = 0;
#pragma unroll
    for (int i = 0; i < 8; i++) cnt[t][myid[i]]++;
    __syncthreads();
    for (int off = 1; off < 256; off <<= 1) {
        int add[NS_];
        if (t >= off)
#pragma unroll
            for (int st = 0; st < NS_; st++) add[st] = cnt[t - off][st];
        __syncthreads();
        if (t >= off)
#pragma unroll
            for (int st = 0; st < NS_; st++) cnt[t][st] += add[st];
        __syncthreads();
    }
#pragma unroll
    for (int st = 0; st < NS_; st++) pre[t][st] = t ? cnt[t - 1][st] : 0;
    if (t == 255)
#pragma unroll
        for (int st = 0; st < NS_; st++) counts[b * NS_ + st] = cnt[255][st];
    __syncthreads();
#pragma unroll
    for (int i = 0; i < 8; i++) {
        int sd = myid[i];
        int r = pre[t][sd]++;
        int pos = t * 8 + i;
        rank[b * L_ + pos] = r;
        poslist[((size_t)b * NS_ + sd) * L_ + r] = pos;
    }
}

// ---------------------------------------------------------------------------
// Kernel 2: MFMA bf16 GEMM C[M,N] = A[M,K] @ B[N,K]^T (unchanged, verified).
// fp32->bf16 fused into staging. c_mode=1: C fp32 when world is fp32.
// ---------------------------------------------------------------------------
__global__ __launch_bounds__(256) void gemm_bt(const void* __restrict__ A,
                                               const void* __restrict__ B,
                                               void* __restrict__ C,
                                               int M, int N, int K,
                                               const int* __restrict__ flags,
                                               int a_force_bf, int c_mode) {
    __shared__ short As[64][40];
    __shared__ short Bs[64][40];
    int tid  = threadIdx.x;
    int wave = tid >> 6, lane = tid & 63;
    int quad = lane >> 4, l16 = lane & 15;
    int bm = blockIdx.y * 64, bn = blockIdx.x * 64;
    int srow = tid >> 2;
    int schunk = (tid & 3) * 8;
    int world_bf = flags[0];
    int abf = a_force_bf ? 1 : world_bf;

    floatx4 acc[2][2] = {};
    int wm = (wave >> 1) * 32;
    int wn = (wave & 1) * 32;

    for (int k0 = 0; k0 < K; k0 += 32) {
        if (abf) {
            *(short8*)&As[srow][schunk] =
                *(const short8*)((const unsigned short*)A + (size_t)(bm + srow) * K + k0 + schunk);
        } else {
            const float* Af = (const float*)A + (size_t)(bm + srow) * K + k0 + schunk;
            float4 f0 = *(const float4*)Af;
            float4 f1 = *(const float4*)(Af + 4);
            short* d = &As[srow][schunk];
            d[0] = (short)f_to_bf16(f0.x); d[1] = (short)f_to_bf16(f0.y);
            d[2] = (short)f_to_bf16(f0.z); d[3] = (short)f_to_bf16(f0.w);
            d[4] = (short)f_to_bf16(f1.x); d[5] = (short)f_to_bf16(f1.y);
            d[6] = (short)f_to_bf16(f1.z); d[7] = (short)f_to_bf16(f1.w);
        }
        if (world_bf) {
            *(short8*)&Bs[srow][schunk] =
                *(const short8*)((const unsigned short*)B + (size_t)(bn + srow) * K + k0 + schunk);
        } else {
            const float* Bf = (const float*)B + (size_t)(bn + srow) * K + k0 + schunk;
            float4 f0 = *(const float4*)Bf;
            float4 f1 = *(const float4*)(Bf + 4);
            short* d = &Bs[srow][schunk];
            d[0] = (short)f_to_bf16(f0.x); d[1] = (short)f_to_bf16(f0.y);
            d[2] = (short)f_to_bf16(f0.z); d[3] = (short)f_to_bf16(f0.w);
            d[4] = (short)f_to_bf16(f1.x); d[5] = (short)f_to_bf16(f1.y);
            d[6] = (short)f_to_bf16(f1.z); d[7] = (short)f_to_bf16(f1.w);
        }
        __syncthreads();
        short8 a0 = *(const short8*)&As[wm + l16][quad * 8];
        short8 a1 = *(const short8*)&As[wm + 16 + l16][quad * 8];
        short8 b0 = *(const short8*)&Bs[wn + l16][quad * 8];
        short8 b1 = *(const short8*)&Bs[wn + 16 + l16][quad * 8];
        acc[0][0] = __builtin_amdgcn_mfma_f32_16x16x32_bf16(a0, b0, acc[0][0], 0, 0, 0);
        acc[0][1] = __builtin_amdgcn_mfma_f32_16x16x32_bf16(a0, b1, acc[0][1], 0, 0, 0);
        acc[1][0] = __builtin_amdgcn_mfma_f32_16x16x32_bf16(a1, b0, acc[1][0], 0, 0, 0);
        acc[1][1] = __builtin_amdgcn_mfma_f32_16x16x32_bf16(a1, b1, acc[1][1], 0, 0, 0);
        __syncthreads();
    }
    int cf32 = (c_mode == 1) && !world_bf;
#pragma unroll
    for (int mt = 0; mt < 2; mt++)
#pragma unroll
        for (int nt = 0; nt < 2; nt++)
#pragma unroll
            for (int r = 0; r < 4; r++) {
                int row = bm + wm + mt * 16 + quad * 4 + r;
                int col = bn + wn + nt * 16 + l16;
                size_t idx = (size_t)row * N + col;
                if (cf32) ((float*)C)[idx] = acc[mt][nt][r];
                else      ((unsigned short*)C)[idx] = f_to_bf16(acc[mt][nt][r]);
            }
}

// ---------------------------------------------------------------------------
// Kernel 3: RoPE in place on bf16 q [BL,16,128] and k [BL,4,128]
// ---------------------------------------------------------------------------
__global__ __launch_bounds__(256) void rope_kernel(unsigned short* __restrict__ q,
                                                   unsigned short* __restrict__ k,
                                                   const int* __restrict__ pos_ids,
                                                   const int* __restrict__ flags) {
    int stride = flags[1];
    int idx = blockIdx.x * 256 + threadIdx.x;
    int i = idx & 63;
    int tmp = idx >> 6;
    int head = tmp % 20;
    int bl = tmp / 20;
    if (bl >= B_ * L_) return;
    float posf = (float)pos_ids[bl * stride];
    float inv = exp2f(-(float)i * (2.0f / 128.0f) * 13.287712379549449f);
    float ang = posf * inv;
    float c = cosf(ang), sn = sinf(ang);
    unsigned short* p = (head < H_) ? (q + ((size_t)bl * H_ + head) * D_)
                                    : (k + ((size_t)bl * KVH_ + (head - H_)) * D_);
    float x0 = bf16_to_f(p[i]), x1 = bf16_to_f(p[i + 64]);
    p[i]      = f_to_bf16(x0 * c - x1 * sn);
    p[i + 64] = f_to_bf16(x1 * c + x0 * sn);
}

// ---------------------------------------------------------------------------
// Kernel 4: MFMA flash attention over packed per-state lists.
// Block = (b, state, kvh, qtile of 16 ranks); 4 waves = 4 GQA q-heads.
// Per 32-key chunk: S = Q·K^T via 8 mfma_16x16x32_bf16, rank-window mask,
// online softmax per q-row, P->bf16 via per-wave LDS (C-layout -> A-frag),
// O += P·V via 8 mfma against LDS-transposed V.
// ---------------------------------------------------------------------------
__global__ __launch_bounds__(256, 2) void attn_mfma(const unsigned short* __restrict__ q,
                                                    const unsigned short* __restrict__ k,
                                                    const unsigned short* __restrict__ v,
                                                    const int* __restrict__ counts,
                                                    const int* __restrict__ poslist,
                                                    unsigned short* __restrict__ o) {
    int qt  = blockIdx.x & 127;
    int kvh = (blockIdx.x >> 7) & 3;
    int s   = (blockIdx.x >> 9) & 7;
    int b   = blockIdx.x >> 12;
    int n = counts[b * NS_ + s];
    if (qt * 16 >= n) return;
    const int* plist = poslist + ((size_t)b * NS_ + s) * L_;

    __shared__ short Ksh[32][136];      // 32 keys x 128 + pad8
    __shared__ short Vsh[128][40];      // transposed: [d][key] + pad8
    __shared__ short Qsh[4][16][136];   // per-wave Q tile
    __shared__ short Psh[4][16][40];    // per-wave P tile
    __shared__ int posq[16];

    int tid = threadIdx.x;
    int wave = tid >> 6, lane = tid & 63;
    int quad = lane >> 4, l16 = lane & 15;
    int h = kvh * 4 + wave;
    const float scale = 0.08838834764831845f;  // 1/sqrt(128)

    if (tid < 16) posq[tid] = plist[min(qt * 16 + tid, n - 1)];
    __syncthreads();

    // stage Q (per wave, own head): lane -> row=lane>>2, 64B seg=lane&3
    {
        int row = lane >> 2, seg = lane & 3;
        const unsigned short* gq =
            q + (((size_t)(b << 11) + posq[row]) * H_ + h) * D_ + seg * 32;
#pragma unroll
        for (int i = 0; i < 4; i++)
            *(short8*)&Qsh[wave][row][seg * 32 + i * 8] = *(const short8*)(gq + i * 8);
    }

    // Q A-frags (loop-invariant): frag kk covers k-dims kk*32 + quad*8..+7
    short8 qf[4];
#pragma unroll
    for (int kk = 0; kk < 4; kk++)
        qf[kk] = *(const short8*)&Qsh[wave][l16][kk * 32 + quad * 8];

    float m_r[4], l_r[4];
    floatx4 Ov[8];
#pragma unroll
    for (int r4 = 0; r4 < 4; r4++) { m_r[r4] = -1e30f; l_r[r4] = 0.f; }
#pragma unroll
    for (int nt = 0; nt < 8; nt++) Ov[nt] = (floatx4){0.f, 0.f, 0.f, 0.f};

    int c0 = max(0, (qt * 16 - WIN_) >> 5);
    int nch = ((qt * 16 + 15) >> 5) + 1;

    for (int c = c0; c < nch; c++) {
        // ---- cooperative K/V staging ----
        {
            int r = tid >> 3, seg = tid & 7;   // r: key row 0..31, seg: 32B
            int kpos = plist[min(c * 32 + r, n - 1)];
            size_t kb = (((size_t)(b << 11) + kpos) * KVH_ + kvh) * (size_t)D_ + seg * 16;
            *(short8*)&Ksh[r][seg * 16]     = *(const short8*)(k + kb);
            *(short8*)&Ksh[r][seg * 16 + 8] = *(const short8*)(k + kb + 8);
            short8 v0 = *(const short8*)(v + kb);
            short8 v1 = *(const short8*)(v + kb + 8);
#pragma unroll
            for (int e = 0; e < 8; e++) Vsh[seg * 16 + e][r] = v0[e];
#pragma unroll
            for (int e = 0; e < 8; e++) Vsh[seg * 16 + 8 + e][r] = v1[e];
        }
        __syncthreads();

        // ---- scores: S[16q x 32k] ----
        floatx4 s0 = (floatx4){0.f, 0.f, 0.f, 0.f};
        floatx4 s1 = (floatx4){0.f, 0.f, 0.f, 0.f};
#pragma unroll
        for (int kk = 0; kk < 4; kk++) {
            short8 kfa = *(const short8*)&Ksh[l16][kk * 32 + quad * 8];
            s0 = __builtin_amdgcn_mfma_f32_16x16x32_bf16(qf[kk], kfa, s0, 0, 0, 0);
        }
#pragma unroll
        for (int kk = 0; kk < 4; kk++) {
            short8 kfb = *(const short8*)&Ksh[16 + l16][kk * 32 + quad * 8];
            s1 = __builtin_amdgcn_mfma_f32_16x16x32_bf16(qf[kk], kfb, s1, 0, 0, 0);
        }

        // ---- mask + online softmax (rows = quad*4+r4, cols = l16 / 16+l16) ----
        int kr0 = c * 32 + l16, kr1 = kr0 + 16;
        float x0[4], x1[4], rmax[4];
#pragma unroll
        for (int r4 = 0; r4 < 4; r4++) {
            int qr = qt * 16 + quad * 4 + r4;
            bool mk0 = (kr0 <= qr) && (kr0 >= qr - WIN_);
            bool mk1 = (kr1 <= qr) && (kr1 >= qr - WIN_);
            x0[r4] = mk0 ? s0[r4] * scale : -1e30f;
            x1[r4] = mk1 ? s1[r4] * scale : -1e30f;
            rmax[r4] = fmaxf(x0[r4], x1[r4]);
        }
#pragma unroll
        for (int st = 1; st <= 8; st <<= 1)
#pragma unroll
            for (int r4 = 0; r4 < 4; r4++)
                rmax[r4] = fmaxf(rmax[r4], __shfl_xor(rmax[r4], st, 64));
        float al[4], psum[4];
#pragma unroll
        for (int r4 = 0; r4 < 4; r4++) {
            float nm = fmaxf(m_r[r4], rmax[r4]);
            al[r4] = __expf(m_r[r4] - nm);
            m_r[r4] = nm;
            x0[r4] = (x0[r4] > -1e29f) ? __expf(x0[r4] - nm) : 0.f;
            x1[r4] = (x1[r4] > -1e29f) ? __expf(x1[r4] - nm) : 0.f;
            psum[r4] = x0[r4] + x1[r4];
        }
#pragma unroll
        for (int st = 1; st <= 8; st <<= 1)
#pragma unroll
            for (int r4 = 0; r4 < 4; r4++)
                psum[r4] += __shfl_xor(psum[r4], st, 64);
#pragma unroll
        for (int r4 = 0; r4 < 4; r4++) l_r[r4] = l_r[r4] * al[r4] + psum[r4];
#pragma unroll
        for (int nt = 0; nt < 8; nt++)
#pragma unroll
            for (int r4 = 0; r4 < 4; r4++) Ov[nt][r4] *= al[r4];

        // ---- P (C-layout) -> bf16 LDS -> A-frag ----
#pragma unroll
        for (int r4 = 0; r4 < 4; r4++) {
            Psh[wave][quad * 4 + r4][l16]      = (short)f_to_bf16(x0[r4]);
            Psh[wave][quad * 4 + r4][16 + l16] = (short)f_to_bf16(x1[r4]);
        }
        short8 pf = *(const short8*)&Psh[wave][l16][quad * 8];

        // ---- O += P·V ----
#pragma unroll
        for (int nt = 0; nt < 8; nt++) {
            short8 vf = *(const short8*)&Vsh[nt * 16 + l16][quad * 8];
            Ov[nt] = __builtin_amdgcn_mfma_f32_16x16x32_bf16(pf, vf, Ov[nt], 0, 0, 0);
        }
        __syncthreads();
    }

    // ---- epilogue: normalize + scatter to o[bl][h][d] ----
    float inv_r[4];
    int pos_r[4], qvalid[4];
#pragma unroll
    for (int r4 = 0; r4 < 4; r4++) {
        int qr = qt * 16 + quad * 4 + r4;
        qvalid[r4] = (qr < n);
        inv_r[r4] = 1.f / l_r[r4];
        pos_r[r4] = posq[quad * 4 + r4];
    }
#pragma unroll
    for (int nt = 0; nt < 8; nt++)
#pragma unroll
        for (int r4 = 0; r4 < 4; r4++)
            if (qvalid[r4])
                o[(((size_t)(b << 11) + pos_r[r4]) * H_ + h) * D_ + nt * 16 + l16] =
                    f_to_bf16(Ov[nt][r4] * inv_r[r4]);
}

// ---------------------------------------------------------------------------
extern "C" void kernel_launch(void* const* d_in, const int* in_sizes, int n_in,
                              void* d_out, int out_size, void* d_ws, size_t ws_size,
                              hipStream_t stream) {
    const void* hs = d_in[0];
    const void* Wq = d_in[1];
    const void* Wk = d_in[2];
    const void* Wv = d_in[3];
    const void* Wo = d_in[4];
    const int* sid  = (const int*)d_in[5];
    const int* pids = (const int*)d_in[6];

    const int M = B_ * L_;  // 4096
    char* w = (char*)d_ws;
    int* flags           = (int*)w;                             //       256 B
    unsigned short* q_b  = (unsigned short*)(w + 256);          // 16,777,216
    unsigned short* k_b  = (unsigned short*)(w + 16777472);     //  4,194,304
    unsigned short* v_b  = (unsigned short*)(w + 20971776);     //  4,194,304
    unsigned short* o_b  = (unsigned short*)(w + 25166080);     // 16,777,216
    int* rank            = (int*)(w + 41943296);                //     16,384
    int* plist           = (int*)(w + 41959680);                //    131,072
    int* counts          = (int*)(w + 42090752);                //        256
    // total ~42.1 MB

    detect_kernel<<<1, 64, 0, stream>>>((const unsigned short*)hs, pids, flags);
    scan_kernel<<<B_, 256, 0, stream>>>(sid, rank, plist, counts, flags);

    gemm_bt<<<dim3(HID_ / 64, M / 64), 256, 0, stream>>>(hs, Wq, q_b, M, H_ * D_, HID_, flags, 0, 0);
    gemm_bt<<<dim3((KVH_ * D_) / 64, M / 64), 256, 0, stream>>>(hs, Wk, k_b, M, KVH_ * D_, HID_, flags, 0, 0);
    gemm_bt<<<dim3((KVH_ * D_) / 64, M / 64), 256, 0, stream>>>(hs, Wv, v_b, M, KVH_ * D_, HID_, flags, 0, 0);

    int rope_threads = M * (H_ + KVH_) * 64;
    rope_kernel<<<(rope_threads + 255) / 256, 256, 0, stream>>>(q_b, k_b, pids, flags);

    // MFMA flash attention: blocks = (b, s, kvh, qtile) = 2*8*4*128
    attn_mfma<<<B_ * NS_ * KVH_ * (L_ / 16), 256, 0, stream>>>(q_b, k_b, v_b, counts, plist, o_b);

    gemm_bt<<<dim3(HID_ / 64, M / 64), 256, 0, stream>>>(o_b, Wo, d_out, M, HID_, HID_, flags, 1, 1);
}

// Round 6
// 364.675 us; speedup vs baseline: 2.9167x; 1.4930x over previous
//
#include <hip/hip_runtime.h>
#include <hip/hip_bf16.h>

#define H_ 16
#define KVH_ 4
#define D_ 128
#define L_ 2048
#define B_ 2
#define HID_ 2048
#define WIN_ 1024
#define NS_ 8
#define QKV_N 3072   // 2048 q + 512 k + 512 v fused

typedef __attribute__((ext_vector_type(8))) short short8;
typedef __attribute__((ext_vector_type(4))) float floatx4;

__device__ inline float bf16_to_f(unsigned short u) {
    union { unsigned int i; float f; } c; c.i = ((unsigned int)u) << 16; return c.f;
}
__device__ inline unsigned short f_to_bf16(float f) {
    __hip_bfloat16 h = __float2bfloat16(f);
    return *(unsigned short*)&h;
}

// ---------------------------------------------------------------------------
// Kernel 0: runtime dtype detection (fp32+int64 expected; bf16/int32 safe).
// ---------------------------------------------------------------------------
__global__ void detect_kernel(const unsigned short* __restrict__ hs_u,
                              const int* __restrict__ pids,
                              int* __restrict__ flags) {
    if (threadIdx.x == 0 && blockIdx.x == 0) {
        int isbf = 1;
        for (int i = 0; i < 32; i++) {
            unsigned short u = hs_u[2 * i];
            int e = (u >> 7) & 0xFF;
            if (e > 130) isbf = 0;
        }
        flags[0] = isbf;
        flags[1] = (pids[1] == 0) ? 2 : 1;
    }
}

// ---------------------------------------------------------------------------
// Kernel 0.5: canonicalize a tensor to bf16 (copy if already bf16, else cvt).
// ---------------------------------------------------------------------------
__global__ __launch_bounds__(256) void convert_kernel(const void* __restrict__ src,
                                                      unsigned short* __restrict__ dst,
                                                      int n4, const int* __restrict__ flags) {
    int isbf = flags[0];
    for (int i = blockIdx.x * 256 + threadIdx.x; i < n4; i += gridDim.x * 256) {
        if (isbf) {
            ((ushort4*)dst)[i] = ((const ushort4*)src)[i];
        } else {
            float4 f = ((const float4*)src)[i];
            ushort4 o;
            o.x = f_to_bf16(f.x); o.y = f_to_bf16(f.y);
            o.z = f_to_bf16(f.z); o.w = f_to_bf16(f.w);
            ((ushort4*)dst)[i] = o;
        }
    }
}

// ---------------------------------------------------------------------------
// Kernel 1: per-batch rank scan + inverse poslist + per-state counts.
// ---------------------------------------------------------------------------
__global__ __launch_bounds__(256) void scan_kernel(const int* __restrict__ sid,
                                                   int* __restrict__ rank,
                                                   int* __restrict__ poslist,
                                                   int* __restrict__ counts,
                                                   const int* __restrict__ flags) {
    int stride = flags[1];
    int b = blockIdx.x;
    int t = threadIdx.x;
    __shared__ int cnt[256][NS_];
    __shared__ int pre[256][NS_];
    const int* s = sid + (size_t)b * L_ * stride;
    int myid[8];
#pragma unroll
    for (int i = 0; i < 8; i++) myid[i] = s[(t * 8 + i) * stride];
#pragma unroll
    for (int st = 0; st < NS_; st++) cnt[t][st] = 0;
#pragma unroll
    for (int i = 0; i < 8; i++) cnt[t][myid[i]]++;
    __syncthreads();
    for (int off = 1; off < 256; off <<= 1) {
        int add[NS_];
        if (t >= off)
#pragma unroll
            for (int st = 0; st < NS_; st++) add[st] = cnt[t - off][st];
        __syncthreads();
        if (t >= off)
#pragma unroll
            for (int st = 0; st < NS_; st++) cnt[t][st] += add[st];
        __syncthreads();
    }
#pragma unroll
    for (int st = 0; st < NS_; st++) pre[t][st] = t ? cnt[t - 1][st] : 0;
    if (t == 255)
#pragma unroll
        for (int st = 0; st < NS_; st++) counts[b * NS_ + st] = cnt[255][st];
    __syncthreads();
#pragma unroll
    for (int i = 0; i < 8; i++) {
        int sd = myid[i];
        int r = pre[t][sd]++;
        int pos = t * 8 + i;
        rank[b * L_ + pos] = r;
        poslist[((size_t)b * NS_ + sd) * L_ + r] = pos;
    }
}

// ---------------------------------------------------------------------------
// Kernel 2: m97-style 128x128 MFMA GEMM, C[M,N] = A[M,K] @ B[N,K]^T.
// All-bf16 inputs. global_load_lds width=16 staging; XOR chunk swizzle
// (applied on the GLOBAL address; LDS side stays wave-uniform + lane*16)
// makes ds_read_b128 fragment reads 2-way (free) instead of 8-way.
// B is segmented over tile-columns (fused QKV): bn_t < nb1 -> B0, < nb2 -> B1,
// else B2. c_fp32: store C as fp32 (harness output in fp32 world).
// ---------------------------------------------------------------------------
__global__ __launch_bounds__(256) void gemm128(const unsigned short* __restrict__ A,
                                               const unsigned short* __restrict__ B0,
                                               const unsigned short* __restrict__ B1,
                                               const unsigned short* __restrict__ B2,
                                               void* __restrict__ C,
                                               int M, int N, int K,
                                               int nb1, int nb2,
                                               const int* __restrict__ flags, int c_mode) {
    __shared__ unsigned short As[128 * 32];
    __shared__ unsigned short Bs[128 * 32];
    int tid = threadIdx.x;
    int wave = tid >> 6, lane = tid & 63;
    int quad = lane >> 4, l16 = lane & 15;
    int bn_t = blockIdx.x;
    int bm = blockIdx.y * 128, bn = bn_t * 128;

    const unsigned short* Bseg;
    int brow0;
    if (bn_t < nb1)      { Bseg = B0; brow0 = bn; }
    else if (bn_t < nb2) { Bseg = B1; brow0 = bn - nb1 * 128; }
    else                 { Bseg = B2; brow0 = bn - nb2 * 128; }

    int srow = tid >> 2;        // 0..63
    int slot = tid & 3;         // 16B chunk slot within row
    int wm = (wave >> 1) * 64, wn = (wave & 1) * 64;

    floatx4 acc[4][4] = {};

    for (int k0 = 0; k0 < K; k0 += 32) {
#pragma unroll
        for (int half = 0; half < 2; half++) {
            int r = srow + half * 64;
            int gc = slot ^ ((r >> 1) & 3);   // global chunk stored at this slot
            const unsigned short* ga = A + (size_t)(bm + r) * K + k0 + gc * 8;
            __builtin_amdgcn_global_load_lds(
                (const __attribute__((address_space(1))) unsigned int*)ga,
                (__attribute__((address_space(3))) unsigned int*)&As[r * 32 + slot * 8],
                16, 0, 0);
            const unsigned short* gb = Bseg + (size_t)(brow0 + r) * K + k0 + gc * 8;
            __builtin_amdgcn_global_load_lds(
                (const __attribute__((address_space(1))) unsigned int*)gb,
                (__attribute__((address_space(3))) unsigned int*)&Bs[r * 32 + slot * 8],
                16, 0, 0);
        }
        __syncthreads();
        short8 af[4], bf[4];
#pragma unroll
        for (int mt = 0; mt < 4; mt++) {
            int r = wm + mt * 16 + l16;
            af[mt] = *(const short8*)&As[r * 32 + (quad ^ ((r >> 1) & 3)) * 8];
        }
#pragma unroll
        for (int nt = 0; nt < 4; nt++) {
            int r = wn + nt * 16 + l16;
            bf[nt] = *(const short8*)&Bs[r * 32 + (quad ^ ((r >> 1) & 3)) * 8];
        }
#pragma unroll
        for (int mt = 0; mt < 4; mt++)
#pragma unroll
            for (int nt = 0; nt < 4; nt++)
                acc[mt][nt] = __builtin_amdgcn_mfma_f32_16x16x32_bf16(af[mt], bf[nt], acc[mt][nt], 0, 0, 0);
        __syncthreads();
    }

    int cf32 = (c_mode == 1) && !flags[0];
    // C/D layout: col = lane&15, row = quad*4 + reg  [m89/m91 verified]
#pragma unroll
    for (int mt = 0; mt < 4; mt++)
#pragma unroll
        for (int nt = 0; nt < 4; nt++)
#pragma unroll
            for (int r = 0; r < 4; r++) {
                int row = bm + wm + mt * 16 + quad * 4 + r;
                int col = bn + wn + nt * 16 + l16;
                size_t idx = (size_t)row * N + col;
                if (cf32) ((float*)C)[idx] = acc[mt][nt][r];
                else      ((unsigned short*)C)[idx] = f_to_bf16(acc[mt][nt][r]);
            }
}

// ---------------------------------------------------------------------------
// Kernel 3: RoPE in place on fused qkv [BL][3072]: heads 0..15 = q at h*128,
// heads 16..19 = k at 2048+(h-16)*128. V untouched.
// ---------------------------------------------------------------------------
__global__ __launch_bounds__(256) void rope_kernel(unsigned short* __restrict__ qkv,
                                                   const int* __restrict__ pos_ids,
                                                   const int* __restrict__ flags) {
    int stride = flags[1];
    int idx = blockIdx.x * 256 + threadIdx.x;
    int i = idx & 63;
    int tmp = idx >> 6;
    int head = tmp % 20;
    int bl = tmp / 20;
    if (bl >= B_ * L_) return;
    float posf = (float)pos_ids[bl * stride];
    float inv = exp2f(-(float)i * (2.0f / 128.0f) * 13.287712379549449f);
    float ang = posf * inv;
    float c = cosf(ang), sn = sinf(ang);
    unsigned short* p = qkv + (size_t)bl * QKV_N +
                        ((head < H_) ? head * D_ : 2048 + (head - H_) * D_);
    float x0 = bf16_to_f(p[i]), x1 = bf16_to_f(p[i + 64]);
    p[i]      = f_to_bf16(x0 * c - x1 * sn);
    p[i + 64] = f_to_bf16(x1 * c + x0 * sn);
}

// ---------------------------------------------------------------------------
// Kernel 4: MFMA flash attention over packed per-state lists (fused qkv in).
// ---------------------------------------------------------------------------
__global__ __launch_bounds__(256, 2) void attn_mfma(const unsigned short* __restrict__ qkv,
                                                    const int* __restrict__ counts,
                                                    const int* __restrict__ poslist,
                                                    unsigned short* __restrict__ o) {
    int qt  = blockIdx.x & 127;
    int kvh = (blockIdx.x >> 7) & 3;
    int s   = (blockIdx.x >> 9) & 7;
    int b   = blockIdx.x >> 12;
    int n = counts[b * NS_ + s];
    if (qt * 16 >= n) return;
    const int* plist = poslist + ((size_t)b * NS_ + s) * L_;

    __shared__ short Ksh[32][136];
    __shared__ short Vsh[128][40];
    __shared__ short Qsh[4][16][136];
    __shared__ short Psh[4][16][40];
    __shared__ int posq[16];

    int tid = threadIdx.x;
    int wave = tid >> 6, lane = tid & 63;
    int quad = lane >> 4, l16 = lane & 15;
    int h = kvh * 4 + wave;
    const float scale = 0.08838834764831845f;

    if (tid < 16) posq[tid] = plist[min(qt * 16 + tid, n - 1)];
    __syncthreads();

    {
        int row = lane >> 2, seg = lane & 3;
        const unsigned short* gq =
            qkv + ((size_t)(b << 11) + posq[row]) * QKV_N + h * D_ + seg * 32;
#pragma unroll
        for (int i = 0; i < 4; i++)
            *(short8*)&Qsh[wave][row][seg * 32 + i * 8] = *(const short8*)(gq + i * 8);
    }

    short8 qf[4];
#pragma unroll
    for (int kk = 0; kk < 4; kk++)
        qf[kk] = *(const short8*)&Qsh[wave][l16][kk * 32 + quad * 8];

    float m_r[4], l_r[4];
    floatx4 Ov[8];
#pragma unroll
    for (int r4 = 0; r4 < 4; r4++) { m_r[r4] = -1e30f; l_r[r4] = 0.f; }
#pragma unroll
    for (int nt = 0; nt < 8; nt++) Ov[nt] = (floatx4){0.f, 0.f, 0.f, 0.f};

    int c0 = max(0, (qt * 16 - WIN_) >> 5);
    int nch = ((qt * 16 + 15) >> 5) + 1;

    for (int c = c0; c < nch; c++) {
        {
            int r = tid >> 3, seg = tid & 7;
            int kpos = plist[min(c * 32 + r, n - 1)];
            size_t base = ((size_t)(b << 11) + kpos) * QKV_N + 2048 + kvh * D_ + seg * 16;
            *(short8*)&Ksh[r][seg * 16]     = *(const short8*)(qkv + base);
            *(short8*)&Ksh[r][seg * 16 + 8] = *(const short8*)(qkv + base + 8);
            short8 v0 = *(const short8*)(qkv + base + 512);
            short8 v1 = *(const short8*)(qkv + base + 520);
#pragma unroll
            for (int e = 0; e < 8; e++) Vsh[seg * 16 + e][r] = v0[e];
#pragma unroll
            for (int e = 0; e < 8; e++) Vsh[seg * 16 + 8 + e][r] = v1[e];
        }
        __syncthreads();

        floatx4 s0 = (floatx4){0.f, 0.f, 0.f, 0.f};
        floatx4 s1 = (floatx4){0.f, 0.f, 0.f, 0.f};
#pragma unroll
        for (int kk = 0; kk < 4; kk++) {
            short8 kfa = *(const short8*)&Ksh[l16][kk * 32 + quad * 8];
            s0 = __builtin_amdgcn_mfma_f32_16x16x32_bf16(qf[kk], kfa, s0, 0, 0, 0);
        }
#pragma unroll
        for (int kk = 0; kk < 4; kk++) {
            short8 kfb = *(const short8*)&Ksh[16 + l16][kk * 32 + quad * 8];
            s1 = __builtin_amdgcn_mfma_f32_16x16x32_bf16(qf[kk], kfb, s1, 0, 0, 0);
        }

        int kr0 = c * 32 + l16, kr1 = kr0 + 16;
        float x0[4], x1[4], rmax[4];
#pragma unroll
        for (int r4 = 0; r4 < 4; r4++) {
            int qr = qt * 16 + quad * 4 + r4;
            bool mk0 = (kr0 <= qr) && (kr0 >= qr - WIN_);
            bool mk1 = (kr1 <= qr) && (kr1 >= qr - WIN_);
            x0[r4] = mk0 ? s0[r4] * scale : -1e30f;
            x1[r4] = mk1 ? s1[r4] * scale : -1e30f;
            rmax[r4] = fmaxf(x0[r4], x1[r4]);
        }
#pragma unroll
        for (int st = 1; st <= 8; st <<= 1)
#pragma unroll
            for (int r4 = 0; r4 < 4; r4++)
                rmax[r4] = fmaxf(rmax[r4], __shfl_xor(rmax[r4], st, 64));
        float al[4], psum[4];
#pragma unroll
        for (int r4 = 0; r4 < 4; r4++) {
            float nm = fmaxf(m_r[r4], rmax[r4]);
            al[r4] = __expf(m_r[r4] - nm);
            m_r[r4] = nm;
            x0[r4] = (x0[r4] > -1e29f) ? __expf(x0[r4] - nm) : 0.f;
            x1[r4] = (x1[r4] > -1e29f) ? __expf(x1[r4] - nm) : 0.f;
            psum[r4] = x0[r4] + x1[r4];
        }
#pragma unroll
        for (int st = 1; st <= 8; st <<= 1)
#pragma unroll
            for (int r4 = 0; r4 < 4; r4++)
                psum[r4] += __shfl_xor(psum[r4], st, 64);
#pragma unroll
        for (int r4 = 0; r4 < 4; r4++) l_r[r4] = l_r[r4] * al[r4] + psum[r4];
#pragma unroll
        for (int nt = 0; nt < 8; nt++)
#pragma unroll
            for (int r4 = 0; r4 < 4; r4++) Ov[nt][r4] *= al[r4];

#pragma unroll
        for (int r4 = 0; r4 < 4; r4++) {
            Psh[wave][quad * 4 + r4][l16]      = (short)f_to_bf16(x0[r4]);
            Psh[wave][quad * 4 + r4][16 + l16] = (short)f_to_bf16(x1[r4]);
        }
        short8 pf = *(const short8*)&Psh[wave][l16][quad * 8];

#pragma unroll
        for (int nt = 0; nt < 8; nt++) {
            short8 vf = *(const short8*)&Vsh[nt * 16 + l16][quad * 8];
            Ov[nt] = __builtin_amdgcn_mfma_f32_16x16x32_bf16(pf, vf, Ov[nt], 0, 0, 0);
        }
        __syncthreads();
    }

    float inv_r[4];
    int pos_r[4], qvalid[4];
#pragma unroll
    for (int r4 = 0; r4 < 4; r4++) {
        int qr = qt * 16 + quad * 4 + r4;
        qvalid[r4] = (qr < n);
        inv_r[r4] = 1.f / l_r[r4];
        pos_r[r4] = posq[quad * 4 + r4];
    }
#pragma unroll
    for (int nt = 0; nt < 8; nt++)
#pragma unroll
        for (int r4 = 0; r4 < 4; r4++)
            if (qvalid[r4])
                o[(((size_t)(b << 11) + pos_r[r4]) * H_ + h) * D_ + nt * 16 + l16] =
                    f_to_bf16(Ov[nt][r4] * inv_r[r4]);
}

// ---------------------------------------------------------------------------
extern "C" void kernel_launch(void* const* d_in, const int* in_sizes, int n_in,
                              void* d_out, int out_size, void* d_ws, size_t ws_size,
                              hipStream_t stream) {
    const void* hs = d_in[0];
    const void* Wq = d_in[1];
    const void* Wk = d_in[2];
    const void* Wv = d_in[3];
    const void* Wo = d_in[4];
    const int* sid  = (const int*)d_in[5];
    const int* pids = (const int*)d_in[6];

    const int M = B_ * L_;  // 4096
    char* w = (char*)d_ws;
    int* flags           = (int*)w;                             //        256 B
    unsigned short* qkv  = (unsigned short*)(w + 256);          // 25,165,824
    unsigned short* o_b  = (unsigned short*)(w + 25166080);     // 16,777,216
    unsigned short* c_hs = (unsigned short*)(w + 41943296);     // 16,777,216
    unsigned short* c_Wq = (unsigned short*)(w + 58720512);     //  8,388,608
    unsigned short* c_Wk = (unsigned short*)(w + 67109120);     //  2,097,152
    unsigned short* c_Wv = (unsigned short*)(w + 69206272);     //  2,097,152
    unsigned short* c_Wo = (unsigned short*)(w + 71303424);     //  8,388,608
    int* rank            = (int*)(w + 79692032);                //     16,384
    int* plist           = (int*)(w + 79708416);                //    131,072
    int* counts          = (int*)(w + 79839488);                //        256
    // total ~79.84 MB

    detect_kernel<<<1, 64, 0, stream>>>((const unsigned short*)hs, pids, flags);

    convert_kernel<<<2048, 256, 0, stream>>>(hs, c_hs, (M * HID_) / 4, flags);
    convert_kernel<<<1024, 256, 0, stream>>>(Wq, c_Wq, (HID_ * HID_) / 4, flags);
    convert_kernel<<<512, 256, 0, stream>>>(Wk, c_Wk, (KVH_ * D_ * HID_) / 4, flags);
    convert_kernel<<<512, 256, 0, stream>>>(Wv, c_Wv, (KVH_ * D_ * HID_) / 4, flags);
    convert_kernel<<<1024, 256, 0, stream>>>(Wo, c_Wo, (HID_ * HID_) / 4, flags);

    scan_kernel<<<B_, 256, 0, stream>>>(sid, rank, plist, counts, flags);

    // fused QKV projection: N = 3072, tiles [0,16)=Wq, [16,20)=Wk, [20,24)=Wv
    gemm128<<<dim3(QKV_N / 128, M / 128), 256, 0, stream>>>(
        c_hs, c_Wq, c_Wk, c_Wv, qkv, M, QKV_N, HID_, 16, 20, flags, 0);

    int rope_threads = M * (H_ + KVH_) * 64;
    rope_kernel<<<(rope_threads + 255) / 256, 256, 0, stream>>>(qkv, pids, flags);

    attn_mfma<<<B_ * NS_ * KVH_ * (L_ / 16), 256, 0, stream>>>(qkv, counts, plist, o_b);

    // output projection (B segments degenerate to Wo)
    gemm128<<<dim3(HID_ / 128, M / 128), 256, 0, stream>>>(
        o_b, c_Wo, c_Wo, c_Wo, d_out, M, HID_, HID_, 1 << 30, 1 << 30, flags, 1);
}

// Round 7
// 340.931 us; speedup vs baseline: 3.1199x; 1.0696x over previous
//
#include <hip/hip_runtime.h>
#include <hip/hip_bf16.h>

#define H_ 16
#define KVH_ 4
#define D_ 128
#define L_ 2048
#define B_ 2
#define HID_ 2048
#define WIN_ 1024
#define NS_ 8
#define QKV_N 3072   // 2048 q + 512 k + 512 v fused

typedef __attribute__((ext_vector_type(8))) short short8;
typedef __attribute__((ext_vector_type(4))) float floatx4;

__device__ inline float bf16_to_f(unsigned short u) {
    union { unsigned int i; float f; } c; c.i = ((unsigned int)u) << 16; return c.f;
}
__device__ inline unsigned short f_to_bf16(float f) {
    __hip_bfloat16 h = __float2bfloat16(f);
    return *(unsigned short*)&h;
}

// ---------------------------------------------------------------------------
// Kernel 0: runtime dtype detection (parallel, 64 samples via ballot).
// ---------------------------------------------------------------------------
__global__ void detect_kernel(const unsigned short* __restrict__ hs_u,
                              const int* __restrict__ pids,
                              int* __restrict__ flags) {
    int lane = threadIdx.x;
    unsigned short u = hs_u[2 * lane];
    int e = (u >> 7) & 0xFF;
    unsigned long long bad = __ballot(e > 130);
    if (lane == 0) {
        flags[0] = (bad == 0ULL) ? 1 : 0;
        flags[1] = (pids[1] == 0) ? 2 : 1;
    }
}

// ---------------------------------------------------------------------------
// Kernel 0.5: canonicalize a tensor to bf16 (copy if already bf16, else cvt).
// ---------------------------------------------------------------------------
__global__ __launch_bounds__(256) void convert_kernel(const void* __restrict__ src,
                                                      unsigned short* __restrict__ dst,
                                                      int n4, const int* __restrict__ flags) {
    int isbf = flags[0];
    for (int i = blockIdx.x * 256 + threadIdx.x; i < n4; i += gridDim.x * 256) {
        if (isbf) {
            ((ushort4*)dst)[i] = ((const ushort4*)src)[i];
        } else {
            float4 f = ((const float4*)src)[i];
            ushort4 o;
            o.x = f_to_bf16(f.x); o.y = f_to_bf16(f.y);
            o.z = f_to_bf16(f.z); o.w = f_to_bf16(f.w);
            ((ushort4*)dst)[i] = o;
        }
    }
}

// ---------------------------------------------------------------------------
// Kernel 1: per-batch rank scan + inverse poslist + per-state counts.
// ---------------------------------------------------------------------------
__global__ __launch_bounds__(256) void scan_kernel(const int* __restrict__ sid,
                                                   int* __restrict__ rank,
                                                   int* __restrict__ poslist,
                                                   int* __restrict__ counts,
                                                   const int* __restrict__ flags) {
    int stride = flags[1];
    int b = blockIdx.x;
    int t = threadIdx.x;
    __shared__ int cnt[256][NS_];
    __shared__ int pre[256][NS_];
    const int* s = sid + (size_t)b * L_ * stride;
    int myid[8];
#pragma unroll
    for (int i = 0; i < 8; i++) myid[i] = s[(t * 8 + i) * stride];
#pragma unroll
    for (int st = 0; st < NS_; st++) cnt[t][st] = 0;
#pragma unroll
    for (int i = 0; i < 8; i++) cnt[t][myid[i]]++;
    __syncthreads();
    for (int off = 1; off < 256; off <<= 1) {
        int add[NS_];
        if (t >= off)
#pragma unroll
            for (int st = 0; st < NS_; st++) add[st] = cnt[t - off][st];
        __syncthreads();
        if (t >= off)
#pragma unroll
            for (int st = 0; st < NS_; st++) cnt[t][st] += add[st];
        __syncthreads();
    }
#pragma unroll
    for (int st = 0; st < NS_; st++) pre[t][st] = t ? cnt[t - 1][st] : 0;
    if (t == 255)
#pragma unroll
        for (int st = 0; st < NS_; st++) counts[b * NS_ + st] = cnt[255][st];
    __syncthreads();
#pragma unroll
    for (int i = 0; i < 8; i++) {
        int sd = myid[i];
        int r = pre[t][sd]++;
        int pos = t * 8 + i;
        rank[b * L_ + pos] = r;
        poslist[((size_t)b * NS_ + sd) * L_ + r] = pos;
    }
}

// ---------------------------------------------------------------------------
// Kernel 2: m97-style 128x128 MFMA GEMM, C[M,N] = A[M,K] @ B[N,K]^T.
// global_load_lds width=16 + XOR chunk swizzle (unchanged from R6, verified).
// ---------------------------------------------------------------------------
__global__ __launch_bounds__(256) void gemm128(const unsigned short* __restrict__ A,
                                               const unsigned short* __restrict__ B0,
                                               const unsigned short* __restrict__ B1,
                                               const unsigned short* __restrict__ B2,
                                               void* __restrict__ C,
                                               int M, int N, int K,
                                               int nb1, int nb2,
                                               const int* __restrict__ flags, int c_mode) {
    __shared__ unsigned short As[128 * 32];
    __shared__ unsigned short Bs[128 * 32];
    int tid = threadIdx.x;
    int wave = tid >> 6, lane = tid & 63;
    int quad = lane >> 4, l16 = lane & 15;
    int bn_t = blockIdx.x;
    int bm = blockIdx.y * 128, bn = bn_t * 128;

    const unsigned short* Bseg;
    int brow0;
    if (bn_t < nb1)      { Bseg = B0; brow0 = bn; }
    else if (bn_t < nb2) { Bseg = B1; brow0 = bn - nb1 * 128; }
    else                 { Bseg = B2; brow0 = bn - nb2 * 128; }

    int srow = tid >> 2;
    int slot = tid & 3;
    int wm = (wave >> 1) * 64, wn = (wave & 1) * 64;

    floatx4 acc[4][4] = {};

    for (int k0 = 0; k0 < K; k0 += 32) {
#pragma unroll
        for (int half = 0; half < 2; half++) {
            int r = srow + half * 64;
            int gc = slot ^ ((r >> 1) & 3);
            const unsigned short* ga = A + (size_t)(bm + r) * K + k0 + gc * 8;
            __builtin_amdgcn_global_load_lds(
                (const __attribute__((address_space(1))) unsigned int*)ga,
                (__attribute__((address_space(3))) unsigned int*)&As[r * 32 + slot * 8],
                16, 0, 0);
            const unsigned short* gb = Bseg + (size_t)(brow0 + r) * K + k0 + gc * 8;
            __builtin_amdgcn_global_load_lds(
                (const __attribute__((address_space(1))) unsigned int*)gb,
                (__attribute__((address_space(3))) unsigned int*)&Bs[r * 32 + slot * 8],
                16, 0, 0);
        }
        __syncthreads();
        short8 af[4], bf[4];
#pragma unroll
        for (int mt = 0; mt < 4; mt++) {
            int r = wm + mt * 16 + l16;
            af[mt] = *(const short8*)&As[r * 32 + (quad ^ ((r >> 1) & 3)) * 8];
        }
#pragma unroll
        for (int nt = 0; nt < 4; nt++) {
            int r = wn + nt * 16 + l16;
            bf[nt] = *(const short8*)&Bs[r * 32 + (quad ^ ((r >> 1) & 3)) * 8];
        }
#pragma unroll
        for (int mt = 0; mt < 4; mt++)
#pragma unroll
            for (int nt = 0; nt < 4; nt++)
                acc[mt][nt] = __builtin_amdgcn_mfma_f32_16x16x32_bf16(af[mt], bf[nt], acc[mt][nt], 0, 0, 0);
        __syncthreads();
    }

    int cf32 = (c_mode == 1) && !flags[0];
#pragma unroll
    for (int mt = 0; mt < 4; mt++)
#pragma unroll
        for (int nt = 0; nt < 4; nt++)
#pragma unroll
            for (int r = 0; r < 4; r++) {
                int row = bm + wm + mt * 16 + quad * 4 + r;
                int col = bn + wn + nt * 16 + l16;
                size_t idx = (size_t)row * N + col;
                if (cf32) ((float*)C)[idx] = acc[mt][nt][r];
                else      ((unsigned short*)C)[idx] = f_to_bf16(acc[mt][nt][r]);
            }
}

// ---------------------------------------------------------------------------
// Kernel 3: RoPE in place on fused qkv [BL][3072].
// ---------------------------------------------------------------------------
__global__ __launch_bounds__(256) void rope_kernel(unsigned short* __restrict__ qkv,
                                                   const int* __restrict__ pos_ids,
                                                   const int* __restrict__ flags) {
    int stride = flags[1];
    int idx = blockIdx.x * 256 + threadIdx.x;
    int i = idx & 63;
    int tmp = idx >> 6;
    int head = tmp % 20;
    int bl = tmp / 20;
    if (bl >= B_ * L_) return;
    float posf = (float)pos_ids[bl * stride];
    float inv = exp2f(-(float)i * (2.0f / 128.0f) * 13.287712379549449f);
    float ang = posf * inv;
    float c = cosf(ang), sn = sinf(ang);
    unsigned short* p = qkv + (size_t)bl * QKV_N +
                        ((head < H_) ? head * D_ : 2048 + (head - H_) * D_);
    float x0 = bf16_to_f(p[i]), x1 = bf16_to_f(p[i + 64]);
    p[i]      = f_to_bf16(x0 * c - x1 * sn);
    p[i + 64] = f_to_bf16(x1 * c + x0 * sn);
}

// ---------------------------------------------------------------------------
// Kernel 4: MFMA flash attention, v2.
//  - no Qsh: Q A-frags loaded directly from global (lane pattern matches)
//  - Vsh column XOR-swizzle: col = key ^ (((d>>4)&3)<<3) -> 4-way max on
//    transpose writes; PV B-frag read stays contiguous short8
//  - register double-buffer: next chunk's plist+K/V prefetched into regs
//    between the barriers, overlapping HBM latency with MFMA/softmax
// ---------------------------------------------------------------------------
__global__ __launch_bounds__(256, 4) void attn_mfma(const unsigned short* __restrict__ qkv,
                                                    const int* __restrict__ counts,
                                                    const int* __restrict__ poslist,
                                                    unsigned short* __restrict__ o) {
    int qt  = blockIdx.x & 127;
    int kvh = (blockIdx.x >> 7) & 3;
    int s   = (blockIdx.x >> 9) & 7;
    int b   = blockIdx.x >> 12;
    int n = counts[b * NS_ + s];
    if (qt * 16 >= n) return;
    const int* plist = poslist + ((size_t)b * NS_ + s) * L_;

    __shared__ short Ksh[32][136];      // [key][d], b128-friendly
    __shared__ short Vsh[128][40];      // [d][key^swz]
    __shared__ short Psh[4][16][40];    // per-wave P round-trip
    __shared__ int posq[16];

    int tid = threadIdx.x;
    int wave = tid >> 6, lane = tid & 63;
    int quad = lane >> 4, l16 = lane & 15;
    int h = kvh * 4 + wave;
    const float scale = 0.08838834764831845f;

    if (tid < 16) posq[tid] = plist[min(qt * 16 + tid, n - 1)];
    __syncthreads();

    // Q A-frags straight from global: A[m=l16][k=quad*8..] per 32-k chunk
    short8 qf[4];
    {
        const unsigned short* gq =
            qkv + ((size_t)(b << 11) + posq[l16]) * QKV_N + h * D_;
#pragma unroll
        for (int kk = 0; kk < 4; kk++)
            qf[kk] = *(const short8*)(gq + kk * 32 + quad * 8);
    }

    float m_r[4], l_r[4];
    floatx4 Ov[8];
#pragma unroll
    for (int r4 = 0; r4 < 4; r4++) { m_r[r4] = -1e30f; l_r[r4] = 0.f; }
#pragma unroll
    for (int nt = 0; nt < 8; nt++) Ov[nt] = (floatx4){0.f, 0.f, 0.f, 0.f};

    int c0 = max(0, (qt * 16 - WIN_) >> 5);
    int nch = ((qt * 16 + 15) >> 5) + 1;

    // staging roles + first-chunk register prefetch
    int r = tid >> 3, seg = tid & 7;
    int vc = r ^ ((seg & 3) << 3);          // swizzled V column for this thread
    short8 kr0, kr1, vr0, vr1;
    {
        int kpos = plist[min(c0 * 32 + r, n - 1)];
        size_t base = ((size_t)(b << 11) + kpos) * QKV_N + 2048 + kvh * D_ + seg * 16;
        kr0 = *(const short8*)(qkv + base);
        kr1 = *(const short8*)(qkv + base + 8);
        vr0 = *(const short8*)(qkv + base + 512);
        vr1 = *(const short8*)(qkv + base + 520);
    }

    for (int c = c0; c < nch; c++) {
        // ---- write staged registers to LDS ----
        *(short8*)&Ksh[r][seg * 16]     = kr0;
        *(short8*)&Ksh[r][seg * 16 + 8] = kr1;
#pragma unroll
        for (int e = 0; e < 8; e++) Vsh[seg * 16 + e][vc] = vr0[e];
#pragma unroll
        for (int e = 0; e < 8; e++) Vsh[seg * 16 + 8 + e][vc] = vr1[e];
        __syncthreads();

        // ---- prefetch next chunk into registers (overlaps compute) ----
        if (c + 1 < nch) {
            int kpos = plist[min((c + 1) * 32 + r, n - 1)];
            size_t base = ((size_t)(b << 11) + kpos) * QKV_N + 2048 + kvh * D_ + seg * 16;
            kr0 = *(const short8*)(qkv + base);
            kr1 = *(const short8*)(qkv + base + 8);
            vr0 = *(const short8*)(qkv + base + 512);
            vr1 = *(const short8*)(qkv + base + 520);
        }

        // ---- scores: S[16q x 32k] ----
        floatx4 s0 = (floatx4){0.f, 0.f, 0.f, 0.f};
        floatx4 s1 = (floatx4){0.f, 0.f, 0.f, 0.f};
#pragma unroll
        for (int kk = 0; kk < 4; kk++) {
            short8 kfa = *(const short8*)&Ksh[l16][kk * 32 + quad * 8];
            s0 = __builtin_amdgcn_mfma_f32_16x16x32_bf16(qf[kk], kfa, s0, 0, 0, 0);
        }
#pragma unroll
        for (int kk = 0; kk < 4; kk++) {
            short8 kfb = *(const short8*)&Ksh[16 + l16][kk * 32 + quad * 8];
            s1 = __builtin_amdgcn_mfma_f32_16x16x32_bf16(qf[kk], kfb, s1, 0, 0, 0);
        }

        // ---- mask + online softmax ----
        int kr0i = c * 32 + l16, kr1i = kr0i + 16;
        float x0[4], x1[4], rmax[4];
#pragma unroll
        for (int r4 = 0; r4 < 4; r4++) {
            int qr = qt * 16 + quad * 4 + r4;
            bool mk0 = (kr0i <= qr) && (kr0i >= qr - WIN_);
            bool mk1 = (kr1i <= qr) && (kr1i >= qr - WIN_);
            x0[r4] = mk0 ? s0[r4] * scale : -1e30f;
            x1[r4] = mk1 ? s1[r4] * scale : -1e30f;
            rmax[r4] = fmaxf(x0[r4], x1[r4]);
        }
#pragma unroll
        for (int st = 1; st <= 8; st <<= 1)
#pragma unroll
            for (int r4 = 0; r4 < 4; r4++)
                rmax[r4] = fmaxf(rmax[r4], __shfl_xor(rmax[r4], st, 64));
        float al[4], psum[4];
#pragma unroll
        for (int r4 = 0; r4 < 4; r4++) {
            float nm = fmaxf(m_r[r4], rmax[r4]);
            al[r4] = __expf(m_r[r4] - nm);
            m_r[r4] = nm;
            x0[r4] = (x0[r4] > -1e29f) ? __expf(x0[r4] - nm) : 0.f;
            x1[r4] = (x1[r4] > -1e29f) ? __expf(x1[r4] - nm) : 0.f;
            psum[r4] = x0[r4] + x1[r4];
        }
#pragma unroll
        for (int st = 1; st <= 8; st <<= 1)
#pragma unroll
            for (int r4 = 0; r4 < 4; r4++)
                psum[r4] += __shfl_xor(psum[r4], st, 64);
#pragma unroll
        for (int r4 = 0; r4 < 4; r4++) l_r[r4] = l_r[r4] * al[r4] + psum[r4];
#pragma unroll
        for (int nt = 0; nt < 8; nt++)
#pragma unroll
            for (int r4 = 0; r4 < 4; r4++) Ov[nt][r4] *= al[r4];

        // ---- P (C-layout) -> bf16 LDS -> A-frag ----
#pragma unroll
        for (int r4 = 0; r4 < 4; r4++) {
            Psh[wave][quad * 4 + r4][l16]      = (short)f_to_bf16(x0[r4]);
            Psh[wave][quad * 4 + r4][16 + l16] = (short)f_to_bf16(x1[r4]);
        }
        short8 pf = *(const short8*)&Psh[wave][l16][quad * 8];

        // ---- O += P·V (V column de-swizzle keeps read contiguous) ----
#pragma unroll
        for (int nt = 0; nt < 8; nt++) {
            short8 vf = *(const short8*)&Vsh[nt * 16 + l16][(quad ^ (nt & 3)) * 8];
            Ov[nt] = __builtin_amdgcn_mfma_f32_16x16x32_bf16(pf, vf, Ov[nt], 0, 0, 0);
        }
        __syncthreads();
    }

    // ---- epilogue ----
    float inv_r[4];
    int pos_r[4], qvalid[4];
#pragma unroll
    for (int r4 = 0; r4 < 4; r4++) {
        int qr = qt * 16 + quad * 4 + r4;
        qvalid[r4] = (qr < n);
        inv_r[r4] = 1.f / l_r[r4];
        pos_r[r4] = posq[quad * 4 + r4];
    }
#pragma unroll
    for (int nt = 0; nt < 8; nt++)
#pragma unroll
        for (int r4 = 0; r4 < 4; r4++)
            if (qvalid[r4])
                o[(((size_t)(b << 11) + pos_r[r4]) * H_ + h) * D_ + nt * 16 + l16] =
                    f_to_bf16(Ov[nt][r4] * inv_r[r4]);
}

// ---------------------------------------------------------------------------
extern "C" void kernel_launch(void* const* d_in, const int* in_sizes, int n_in,
                              void* d_out, int out_size, void* d_ws, size_t ws_size,
                              hipStream_t stream) {
    const void* hs = d_in[0];
    const void* Wq = d_in[1];
    const void* Wk = d_in[2];
    const void* Wv = d_in[3];
    const void* Wo = d_in[4];
    const int* sid  = (const int*)d_in[5];
    const int* pids = (const int*)d_in[6];

    const int M = B_ * L_;  // 4096
    char* w = (char*)d_ws;
    int* flags           = (int*)w;                             //        256 B
    unsigned short* qkv  = (unsigned short*)(w + 256);          // 25,165,824
    unsigned short* o_b  = (unsigned short*)(w + 25166080);     // 16,777,216
    unsigned short* c_hs = (unsigned short*)(w + 41943296);     // 16,777,216
    unsigned short* c_Wq = (unsigned short*)(w + 58720512);     //  8,388,608
    unsigned short* c_Wk = (unsigned short*)(w + 67109120);     //  2,097,152
    unsigned short* c_Wv = (unsigned short*)(w + 69206272);     //  2,097,152
    unsigned short* c_Wo = (unsigned short*)(w + 71303424);     //  8,388,608
    int* rank            = (int*)(w + 79692032);                //     16,384
    int* plist           = (int*)(w + 79708416);                //    131,072
    int* counts          = (int*)(w + 79839488);                //        256

    detect_kernel<<<1, 64, 0, stream>>>((const unsigned short*)hs, pids, flags);

    convert_kernel<<<2048, 256, 0, stream>>>(hs, c_hs, (M * HID_) / 4, flags);
    convert_kernel<<<1024, 256, 0, stream>>>(Wq, c_Wq, (HID_ * HID_) / 4, flags);
    convert_kernel<<<512, 256, 0, stream>>>(Wk, c_Wk, (KVH_ * D_ * HID_) / 4, flags);
    convert_kernel<<<512, 256, 0, stream>>>(Wv, c_Wv, (KVH_ * D_ * HID_) / 4, flags);
    convert_kernel<<<1024, 256, 0, stream>>>(Wo, c_Wo, (HID_ * HID_) / 4, flags);

    scan_kernel<<<B_, 256, 0, stream>>>(sid, rank, plist, counts, flags);

    gemm128<<<dim3(QKV_N / 128, M / 128), 256, 0, stream>>>(
        c_hs, c_Wq, c_Wk, c_Wv, qkv, M, QKV_N, HID_, 16, 20, flags, 0);

    int rope_threads = M * (H_ + KVH_) * 64;
    rope_kernel<<<(rope_threads + 255) / 256, 256, 0, stream>>>(qkv, pids, flags);

    attn_mfma<<<B_ * NS_ * KVH_ * (L_ / 16), 256, 0, stream>>>(qkv, counts, plist, o_b);

    gemm128<<<dim3(HID_ / 128, M / 128), 256, 0, stream>>>(
        o_b, c_Wo, c_Wo, c_Wo, d_out, M, HID_, HID_, 1 << 30, 1 << 30, flags, 1);
}

// Round 8
// 335.176 us; speedup vs baseline: 3.1734x; 1.0172x over previous
//
#include <hip/hip_runtime.h>
#include <hip/hip_bf16.h>

#define H_ 16
#define KVH_ 4
#define D_ 128
#define L_ 2048
#define B_ 2
#define HID_ 2048
#define WIN_ 1024
#define NS_ 8
#define QKV_N 3072   // 2048 q + 512 k + 512 v fused

typedef __attribute__((ext_vector_type(8))) short short8;
typedef __attribute__((ext_vector_type(4))) float floatx4;

__device__ inline float bf16_to_f(unsigned short u) {
    union { unsigned int i; float f; } c; c.i = ((unsigned int)u) << 16; return c.f;
}
__device__ inline unsigned short f_to_bf16(float f) {
    __hip_bfloat16 h = __float2bfloat16(f);
    return *(unsigned short*)&h;
}

// ---------------------------------------------------------------------------
// Kernel 0: runtime dtype detection (parallel, 64 samples via ballot).
// ---------------------------------------------------------------------------
__global__ void detect_kernel(const unsigned short* __restrict__ hs_u,
                              const int* __restrict__ pids,
                              int* __restrict__ flags) {
    int lane = threadIdx.x;
    unsigned short u = hs_u[2 * lane];
    int e = (u >> 7) & 0xFF;
    unsigned long long bad = __ballot(e > 130);
    if (lane == 0) {
        flags[0] = (bad == 0ULL) ? 1 : 0;
        flags[1] = (pids[1] == 0) ? 2 : 1;
    }
}

// ---------------------------------------------------------------------------
// Kernel 0.5: canonicalize a tensor to bf16 (copy if already bf16, else cvt).
// ---------------------------------------------------------------------------
__global__ __launch_bounds__(256) void convert_kernel(const void* __restrict__ src,
                                                      unsigned short* __restrict__ dst,
                                                      int n4, const int* __restrict__ flags) {
    int isbf = flags[0];
    for (int i = blockIdx.x * 256 + threadIdx.x; i < n4; i += gridDim.x * 256) {
        if (isbf) {
            ((ushort4*)dst)[i] = ((const ushort4*)src)[i];
        } else {
            float4 f = ((const float4*)src)[i];
            ushort4 o;
            o.x = f_to_bf16(f.x); o.y = f_to_bf16(f.y);
            o.z = f_to_bf16(f.z); o.w = f_to_bf16(f.w);
            ((ushort4*)dst)[i] = o;
        }
    }
}

// ---------------------------------------------------------------------------
// Kernel 1: per-batch rank scan + inverse poslist + per-state counts.
// ---------------------------------------------------------------------------
__global__ __launch_bounds__(256) void scan_kernel(const int* __restrict__ sid,
                                                   int* __restrict__ rank,
                                                   int* __restrict__ poslist,
                                                   int* __restrict__ counts,
                                                   const int* __restrict__ flags) {
    int stride = flags[1];
    int b = blockIdx.x;
    int t = threadIdx.x;
    __shared__ int cnt[256][NS_];
    __shared__ int pre[256][NS_];
    const int* s = sid + (size_t)b * L_ * stride;
    int myid[8];
#pragma unroll
    for (int i = 0; i < 8; i++) myid[i] = s[(t * 8 + i) * stride];
#pragma unroll
    for (int st = 0; st < NS_; st++) cnt[t][st] = 0;
#pragma unroll
    for (int i = 0; i < 8; i++) cnt[t][myid[i]]++;
    __syncthreads();
    for (int off = 1; off < 256; off <<= 1) {
        int add[NS_];
        if (t >= off)
#pragma unroll
            for (int st = 0; st < NS_; st++) add[st] = cnt[t - off][st];
        __syncthreads();
        if (t >= off)
#pragma unroll
            for (int st = 0; st < NS_; st++) cnt[t][st] += add[st];
        __syncthreads();
    }
#pragma unroll
    for (int st = 0; st < NS_; st++) pre[t][st] = t ? cnt[t - 1][st] : 0;
    if (t == 255)
#pragma unroll
        for (int st = 0; st < NS_; st++) counts[b * NS_ + st] = cnt[255][st];
    __syncthreads();
#pragma unroll
    for (int i = 0; i < 8; i++) {
        int sd = myid[i];
        int r = pre[t][sd]++;
        int pos = t * 8 + i;
        rank[b * L_ + pos] = r;
        poslist[((size_t)b * NS_ + sd) * L_ + r] = pos;
    }
}

// ---------------------------------------------------------------------------
// Kernel 2: 128x128 MFMA GEMM, BK=64: C[M,N] = A[M,K] @ B[N,K]^T.
// 32 MFMA + 16 ds_read_b128 per barrier (half the barrier drains of BK=32).
// Staging: 4 passes x 256 lanes of global_load_lds width=16; LDS slot tid
// keeps dest wave-uniform+lane*16. XOR swizzle slot = chunk ^ (row&7)
// (row stride 8 chunks) -> frag ds_read_b128 is 2-way (free).
// B segmented over tile-columns for fused QKV.
// ---------------------------------------------------------------------------
__global__ __launch_bounds__(256) void gemm128(const unsigned short* __restrict__ A,
                                               const unsigned short* __restrict__ B0,
                                               const unsigned short* __restrict__ B1,
                                               const unsigned short* __restrict__ B2,
                                               void* __restrict__ C,
                                               int M, int N, int K,
                                               int nb1, int nb2,
                                               const int* __restrict__ flags, int c_mode) {
    __shared__ unsigned short As[128 * 64];   // 16 KB
    __shared__ unsigned short Bs[128 * 64];   // 16 KB
    int tid = threadIdx.x;
    int wave = tid >> 6, lane = tid & 63;
    int quad = lane >> 4, l16 = lane & 15;
    int bn_t = blockIdx.x;
    int bm = blockIdx.y * 128, bn = bn_t * 128;

    const unsigned short* Bseg;
    int brow0;
    if (bn_t < nb1)      { Bseg = B0; brow0 = bn; }
    else if (bn_t < nb2) { Bseg = B1; brow0 = bn - nb1 * 128; }
    else                 { Bseg = B2; brow0 = bn - nb2 * 128; }

    int wm = (wave >> 1) * 64, wn = (wave & 1) * 64;

    // staging geometry (constant per thread, per pass)
    int srow[4], sgc[4];
#pragma unroll
    for (int p = 0; p < 4; p++) {
        int si = p * 256 + tid;
        int row = si >> 3, sl = si & 7;
        srow[p] = row;
        sgc[p] = sl ^ (row & 7);
    }

    floatx4 acc[4][4] = {};

    for (int k0 = 0; k0 < K; k0 += 64) {
#pragma unroll
        for (int p = 0; p < 4; p++) {
            int si = p * 256 + tid;
            const unsigned short* ga = A + (size_t)(bm + srow[p]) * K + k0 + sgc[p] * 8;
            __builtin_amdgcn_global_load_lds(
                (const __attribute__((address_space(1))) unsigned int*)ga,
                (__attribute__((address_space(3))) unsigned int*)&As[si * 8],
                16, 0, 0);
            const unsigned short* gb = Bseg + (size_t)(brow0 + srow[p]) * K + k0 + sgc[p] * 8;
            __builtin_amdgcn_global_load_lds(
                (const __attribute__((address_space(1))) unsigned int*)gb,
                (__attribute__((address_space(3))) unsigned int*)&Bs[si * 8],
                16, 0, 0);
        }
        __syncthreads();
#pragma unroll
        for (int ks = 0; ks < 2; ks++) {
            short8 af[4], bf[4];
#pragma unroll
            for (int mt = 0; mt < 4; mt++) {
                int r = wm + mt * 16 + l16;
                int slot = (ks * 4 + quad) ^ (r & 7);
                af[mt] = *(const short8*)&As[r * 64 + slot * 8];
            }
#pragma unroll
            for (int nt = 0; nt < 4; nt++) {
                int r = wn + nt * 16 + l16;
                int slot = (ks * 4 + quad) ^ (r & 7);
                bf[nt] = *(const short8*)&Bs[r * 64 + slot * 8];
            }
#pragma unroll
            for (int mt = 0; mt < 4; mt++)
#pragma unroll
                for (int nt = 0; nt < 4; nt++)
                    acc[mt][nt] = __builtin_amdgcn_mfma_f32_16x16x32_bf16(af[mt], bf[nt], acc[mt][nt], 0, 0, 0);
        }
        __syncthreads();
    }

    int cf32 = (c_mode == 1) && !flags[0];
    // C/D layout: col = lane&15, row = quad*4 + reg  [m89/m91 verified]
#pragma unroll
    for (int mt = 0; mt < 4; mt++)
#pragma unroll
        for (int nt = 0; nt < 4; nt++)
#pragma unroll
            for (int r = 0; r < 4; r++) {
                int row = bm + wm + mt * 16 + quad * 4 + r;
                int col = bn + wn + nt * 16 + l16;
                size_t idx = (size_t)row * N + col;
                if (cf32) ((float*)C)[idx] = acc[mt][nt][r];
                else      ((unsigned short*)C)[idx] = f_to_bf16(acc[mt][nt][r]);
            }
}

// ---------------------------------------------------------------------------
// Kernel 3: RoPE in place on fused qkv [BL][3072].
// ---------------------------------------------------------------------------
__global__ __launch_bounds__(256) void rope_kernel(unsigned short* __restrict__ qkv,
                                                   const int* __restrict__ pos_ids,
                                                   const int* __restrict__ flags) {
    int stride = flags[1];
    int idx = blockIdx.x * 256 + threadIdx.x;
    int i = idx & 63;
    int tmp = idx >> 6;
    int head = tmp % 20;
    int bl = tmp / 20;
    if (bl >= B_ * L_) return;
    float posf = (float)pos_ids[bl * stride];
    float inv = exp2f(-(float)i * (2.0f / 128.0f) * 13.287712379549449f);
    float ang = posf * inv;
    float c = cosf(ang), sn = sinf(ang);
    unsigned short* p = qkv + (size_t)bl * QKV_N +
                        ((head < H_) ? head * D_ : 2048 + (head - H_) * D_);
    float x0 = bf16_to_f(p[i]), x1 = bf16_to_f(p[i + 64]);
    p[i]      = f_to_bf16(x0 * c - x1 * sn);
    p[i + 64] = f_to_bf16(x1 * c + x0 * sn);
}

// ---------------------------------------------------------------------------
// Kernel 4: MFMA flash attention (unchanged from R7 — verified fast).
// ---------------------------------------------------------------------------
__global__ __launch_bounds__(256, 4) void attn_mfma(const unsigned short* __restrict__ qkv,
                                                    const int* __restrict__ counts,
                                                    const int* __restrict__ poslist,
                                                    unsigned short* __restrict__ o) {
    int qt  = blockIdx.x & 127;
    int kvh = (blockIdx.x >> 7) & 3;
    int s   = (blockIdx.x >> 9) & 7;
    int b   = blockIdx.x >> 12;
    int n = counts[b * NS_ + s];
    if (qt * 16 >= n) return;
    const int* plist = poslist + ((size_t)b * NS_ + s) * L_;

    __shared__ short Ksh[32][136];
    __shared__ short Vsh[128][40];
    __shared__ short Psh[4][16][40];
    __shared__ int posq[16];

    int tid = threadIdx.x;
    int wave = tid >> 6, lane = tid & 63;
    int quad = lane >> 4, l16 = lane & 15;
    int h = kvh * 4 + wave;
    const float scale = 0.08838834764831845f;

    if (tid < 16) posq[tid] = plist[min(qt * 16 + tid, n - 1)];
    __syncthreads();

    short8 qf[4];
    {
        const unsigned short* gq =
            qkv + ((size_t)(b << 11) + posq[l16]) * QKV_N + h * D_;
#pragma unroll
        for (int kk = 0; kk < 4; kk++)
            qf[kk] = *(const short8*)(gq + kk * 32 + quad * 8);
    }

    float m_r[4], l_r[4];
    floatx4 Ov[8];
#pragma unroll
    for (int r4 = 0; r4 < 4; r4++) { m_r[r4] = -1e30f; l_r[r4] = 0.f; }
#pragma unroll
    for (int nt = 0; nt < 8; nt++) Ov[nt] = (floatx4){0.f, 0.f, 0.f, 0.f};

    int c0 = max(0, (qt * 16 - WIN_) >> 5);
    int nch = ((qt * 16 + 15) >> 5) + 1;

    int r = tid >> 3, seg = tid & 7;
    int vc = r ^ ((seg & 3) << 3);
    short8 kr0, kr1, vr0, vr1;
    {
        int kpos = plist[min(c0 * 32 + r, n - 1)];
        size_t base = ((size_t)(b << 11) + kpos) * QKV_N + 2048 + kvh * D_ + seg * 16;
        kr0 = *(const short8*)(qkv + base);
        kr1 = *(const short8*)(qkv + base + 8);
        vr0 = *(const short8*)(qkv + base + 512);
        vr1 = *(const short8*)(qkv + base + 520);
    }

    for (int c = c0; c < nch; c++) {
        *(short8*)&Ksh[r][seg * 16]     = kr0;
        *(short8*)&Ksh[r][seg * 16 + 8] = kr1;
#pragma unroll
        for (int e = 0; e < 8; e++) Vsh[seg * 16 + e][vc] = vr0[e];
#pragma unroll
        for (int e = 0; e < 8; e++) Vsh[seg * 16 + 8 + e][vc] = vr1[e];
        __syncthreads();

        if (c + 1 < nch) {
            int kpos = plist[min((c + 1) * 32 + r, n - 1)];
            size_t base = ((size_t)(b << 11) + kpos) * QKV_N + 2048 + kvh * D_ + seg * 16;
            kr0 = *(const short8*)(qkv + base);
            kr1 = *(const short8*)(qkv + base + 8);
            vr0 = *(const short8*)(qkv + base + 512);
            vr1 = *(const short8*)(qkv + base + 520);
        }

        floatx4 s0 = (floatx4){0.f, 0.f, 0.f, 0.f};
        floatx4 s1 = (floatx4){0.f, 0.f, 0.f, 0.f};
#pragma unroll
        for (int kk = 0; kk < 4; kk++) {
            short8 kfa = *(const short8*)&Ksh[l16][kk * 32 + quad * 8];
            s0 = __builtin_amdgcn_mfma_f32_16x16x32_bf16(qf[kk], kfa, s0, 0, 0, 0);
        }
#pragma unroll
        for (int kk = 0; kk < 4; kk++) {
            short8 kfb = *(const short8*)&Ksh[16 + l16][kk * 32 + quad * 8];
            s1 = __builtin_amdgcn_mfma_f32_16x16x32_bf16(qf[kk], kfb, s1, 0, 0, 0);
        }

        int kr0i = c * 32 + l16, kr1i = kr0i + 16;
        float x0[4], x1[4], rmax[4];
#pragma unroll
        for (int r4 = 0; r4 < 4; r4++) {
            int qr = qt * 16 + quad * 4 + r4;
            bool mk0 = (kr0i <= qr) && (kr0i >= qr - WIN_);
            bool mk1 = (kr1i <= qr) && (kr1i >= qr - WIN_);
            x0[r4] = mk0 ? s0[r4] * scale : -1e30f;
            x1[r4] = mk1 ? s1[r4] * scale : -1e30f;
            rmax[r4] = fmaxf(x0[r4], x1[r4]);
        }
#pragma unroll
        for (int st = 1; st <= 8; st <<= 1)
#pragma unroll
            for (int r4 = 0; r4 < 4; r4++)
                rmax[r4] = fmaxf(rmax[r4], __shfl_xor(rmax[r4], st, 64));
        float al[4], psum[4];
#pragma unroll
        for (int r4 = 0; r4 < 4; r4++) {
            float nm = fmaxf(m_r[r4], rmax[r4]);
            al[r4] = __expf(m_r[r4] - nm);
            m_r[r4] = nm;
            x0[r4] = (x0[r4] > -1e29f) ? __expf(x0[r4] - nm) : 0.f;
            x1[r4] = (x1[r4] > -1e29f) ? __expf(x1[r4] - nm) : 0.f;
            psum[r4] = x0[r4] + x1[r4];
        }
#pragma unroll
        for (int st = 1; st <= 8; st <<= 1)
#pragma unroll
            for (int r4 = 0; r4 < 4; r4++)
                psum[r4] += __shfl_xor(psum[r4], st, 64);
#pragma unroll
        for (int r4 = 0; r4 < 4; r4++) l_r[r4] = l_r[r4] * al[r4] + psum[r4];
#pragma unroll
        for (int nt = 0; nt < 8; nt++)
#pragma unroll
            for (int r4 = 0; r4 < 4; r4++) Ov[nt][r4] *= al[r4];

#pragma unroll
        for (int r4 = 0; r4 < 4; r4++) {
            Psh[wave][quad * 4 + r4][l16]      = (short)f_to_bf16(x0[r4]);
            Psh[wave][quad * 4 + r4][16 + l16] = (short)f_to_bf16(x1[r4]);
        }
        short8 pf = *(const short8*)&Psh[wave][l16][quad * 8];

#pragma unroll
        for (int nt = 0; nt < 8; nt++) {
            short8 vf = *(const short8*)&Vsh[nt * 16 + l16][(quad ^ (nt & 3)) * 8];
            Ov[nt] = __builtin_amdgcn_mfma_f32_16x16x32_bf16(pf, vf, Ov[nt], 0, 0, 0);
        }
        __syncthreads();
    }

    float inv_r[4];
    int pos_r[4], qvalid[4];
#pragma unroll
    for (int r4 = 0; r4 < 4; r4++) {
        int qr = qt * 16 + quad * 4 + r4;
        qvalid[r4] = (qr < n);
        inv_r[r4] = 1.f / l_r[r4];
        pos_r[r4] = posq[quad * 4 + r4];
    }
#pragma unroll
    for (int nt = 0; nt < 8; nt++)
#pragma unroll
        for (int r4 = 0; r4 < 4; r4++)
            if (qvalid[r4])
                o[(((size_t)(b << 11) + pos_r[r4]) * H_ + h) * D_ + nt * 16 + l16] =
                    f_to_bf16(Ov[nt][r4] * inv_r[r4]);
}

// ---------------------------------------------------------------------------
extern "C" void kernel_launch(void* const* d_in, const int* in_sizes, int n_in,
                              void* d_out, int out_size, void* d_ws, size_t ws_size,
                              hipStream_t stream) {
    const void* hs = d_in[0];
    const void* Wq = d_in[1];
    const void* Wk = d_in[2];
    const void* Wv = d_in[3];
    const void* Wo = d_in[4];
    const int* sid  = (const int*)d_in[5];
    const int* pids = (const int*)d_in[6];

    const int M = B_ * L_;  // 4096
    char* w = (char*)d_ws;
    int* flags           = (int*)w;                             //        256 B
    unsigned short* qkv  = (unsigned short*)(w + 256);          // 25,165,824
    unsigned short* o_b  = (unsigned short*)(w + 25166080);     // 16,777,216
    unsigned short* c_hs = (unsigned short*)(w + 41943296);     // 16,777,216
    unsigned short* c_Wq = (unsigned short*)(w + 58720512);     //  8,388,608
    unsigned short* c_Wk = (unsigned short*)(w + 67109120);     //  2,097,152
    unsigned short* c_Wv = (unsigned short*)(w + 69206272);     //  2,097,152
    unsigned short* c_Wo = (unsigned short*)(w + 71303424);     //  8,388,608
    int* rank            = (int*)(w + 79692032);                //     16,384
    int* plist           = (int*)(w + 79708416);                //    131,072
    int* counts          = (int*)(w + 79839488);                //        256

    detect_kernel<<<1, 64, 0, stream>>>((const unsigned short*)hs, pids, flags);

    convert_kernel<<<2048, 256, 0, stream>>>(hs, c_hs, (M * HID_) / 4, flags);
    convert_kernel<<<1024, 256, 0, stream>>>(Wq, c_Wq, (HID_ * HID_) / 4, flags);
    convert_kernel<<<512, 256, 0, stream>>>(Wk, c_Wk, (KVH_ * D_ * HID_) / 4, flags);
    convert_kernel<<<512, 256, 0, stream>>>(Wv, c_Wv, (KVH_ * D_ * HID_) / 4, flags);
    convert_kernel<<<1024, 256, 0, stream>>>(Wo, c_Wo, (HID_ * HID_) / 4, flags);

    scan_kernel<<<B_, 256, 0, stream>>>(sid, rank, plist, counts, flags);

    gemm128<<<dim3(QKV_N / 128, M / 128), 256, 0, stream>>>(
        c_hs, c_Wq, c_Wk, c_Wv, qkv, M, QKV_N, HID_, 16, 20, flags, 0);

    int rope_threads = M * (H_ + KVH_) * 64;
    rope_kernel<<<(rope_threads + 255) / 256, 256, 0, stream>>>(qkv, pids, flags);

    attn_mfma<<<B_ * NS_ * KVH_ * (L_ / 16), 256, 0, stream>>>(qkv, counts, plist, o_b);

    gemm128<<<dim3(HID_ / 128, M / 128), 256, 0, stream>>>(
        o_b, c_Wo, c_Wo, c_Wo, d_out, M, HID_, HID_, 1 << 30, 1 << 30, flags, 1);
}

// Round 9
// 331.539 us; speedup vs baseline: 3.2083x; 1.0110x over previous
//
#include <hip/hip_runtime.h>
#include <hip/hip_bf16.h>

#define H_ 16
#define KVH_ 4
#define D_ 128
#define L_ 2048
#define B_ 2
#define HID_ 2048
#define WIN_ 1024
#define NS_ 8
#define QKV_N 3072   // 2048 q + 512 k + 512 v fused

typedef __attribute__((ext_vector_type(8))) short short8;
typedef __attribute__((ext_vector_type(4))) float floatx4;

__device__ inline float bf16_to_f(unsigned short u) {
    union { unsigned int i; float f; } c; c.i = ((unsigned int)u) << 16; return c.f;
}
__device__ inline unsigned short f_to_bf16(float f) {
    __hip_bfloat16 h = __float2bfloat16(f);
    return *(unsigned short*)&h;
}

// ---------------------------------------------------------------------------
// Inline dtype detection (replaces detect_kernel + flags buffer).
// World probe: lanes sample 32 u16 words of hidden_states; in bf16 world the
// exponent field of N(0,1) bf16s is <=130 (P(fail)~1e-15); in fp32 world these
// are uniform mantissa words (P(all<=130) ~ 5e-10). Wave-uniform via ballot.
// Int stride: position_ids is tiled arange -> pids[1]==0 iff int64.
// ---------------------------------------------------------------------------
__device__ inline int world_is_bf16(const unsigned short* hs_u) {
    int lane = threadIdx.x & 63;
    unsigned short u = hs_u[(lane & 31) * 2];
    int e = (u >> 7) & 0xFF;
    unsigned long long bad = __ballot(e > 130);
    return bad == 0ULL;
}
__device__ inline int pid_stride(const int* pids) { return (pids[1] == 0) ? 2 : 1; }

// ---------------------------------------------------------------------------
// Kernel A: fused canonicalization of all 5 float tensors to bf16 (1 launch).
// ---------------------------------------------------------------------------
__global__ __launch_bounds__(256) void convert_all(const void* __restrict__ hs,
                                                   const void* __restrict__ Wq,
                                                   const void* __restrict__ Wk,
                                                   const void* __restrict__ Wv,
                                                   const void* __restrict__ Wo,
                                                   unsigned short* __restrict__ c_hs,
                                                   unsigned short* __restrict__ c_Wq,
                                                   unsigned short* __restrict__ c_Wk,
                                                   unsigned short* __restrict__ c_Wv,
                                                   unsigned short* __restrict__ c_Wo) {
    int isbf = world_is_bf16((const unsigned short*)hs);
    const int N0 = (B_ * L_ * HID_) / 4;        // hs   2,097,152
    const int N1 = (HID_ * HID_) / 4;           // Wq   1,048,576
    const int N2 = (KVH_ * D_ * HID_) / 4;      // Wk     262,144
    const int N3 = N2;                          // Wv
    const int N4 = N1;                          // Wo
    const int total = N0 + N1 + N2 + N3 + N4;
    for (int i = blockIdx.x * 256 + threadIdx.x; i < total; i += gridDim.x * 256) {
        int j = i;
        const void* src; unsigned short* dst;
        if (j < N0)              { src = hs; dst = c_hs; }
        else if ((j -= N0) < N1) { src = Wq; dst = c_Wq; }
        else if ((j -= N1) < N2) { src = Wk; dst = c_Wk; }
        else if ((j -= N2) < N3) { src = Wv; dst = c_Wv; }
        else                     { j -= N3; src = Wo; dst = c_Wo; }
        if (isbf) {
            ((ushort4*)dst)[j] = ((const ushort4*)src)[j];
        } else {
            float4 f = ((const float4*)src)[j];
            ushort4 o4;
            o4.x = f_to_bf16(f.x); o4.y = f_to_bf16(f.y);
            o4.z = f_to_bf16(f.z); o4.w = f_to_bf16(f.w);
            ((ushort4*)dst)[j] = o4;
        }
    }
}

// ---------------------------------------------------------------------------
// Kernel 1: per-batch rank scan + inverse poslist + per-state counts.
// ---------------------------------------------------------------------------
__global__ __launch_bounds__(256) void scan_kernel(const int* __restrict__ sid,
                                                   const int* __restrict__ pids,
                                                   int* __restrict__ rank,
                                                   int* __restrict__ poslist,
                                                   int* __restrict__ counts) {
    int stride = pid_stride(pids);
    int b = blockIdx.x;
    int t = threadIdx.x;
    __shared__ int cnt[256][NS_];
    __shared__ int pre[256][NS_];
    const int* s = sid + (size_t)b * L_ * stride;
    int myid[8];
#pragma unroll
    for (int i = 0; i < 8; i++) myid[i] = s[(t * 8 + i) * stride];
#pragma unroll
    for (int st = 0; st < NS_; st++) cnt[t][st] = 0;
#pragma unroll
    for (int i = 0; i < 8; i++) cnt[t][myid[i]]++;
    __syncthreads();
    for (int off = 1; off < 256; off <<= 1) {
        int add[NS_];
        if (t >= off)
#pragma unroll
            for (int st = 0; st < NS_; st++) add[st] = cnt[t - off][st];
        __syncthreads();
        if (t >= off)
#pragma unroll
            for (int st = 0; st < NS_; st++) cnt[t][st] += add[st];
        __syncthreads();
    }
#pragma unroll
    for (int st = 0; st < NS_; st++) pre[t][st] = t ? cnt[t - 1][st] : 0;
    if (t == 255)
#pragma unroll
        for (int st = 0; st < NS_; st++) counts[b * NS_ + st] = cnt[255][st];
    __syncthreads();
#pragma unroll
    for (int i = 0; i < 8; i++) {
        int sd = myid[i];
        int r = pre[t][sd]++;
        int pos = t * 8 + i;
        rank[b * L_ + pos] = r;
        poslist[((size_t)b * NS_ + sd) * L_ + r] = pos;
    }
}

// ---------------------------------------------------------------------------
// Kernel 2: 128x128 MFMA GEMM, BK=32 (R7 body — measured faster than BK=64).
// global_load_lds width=16 + XOR chunk swizzle; B segmented for fused QKV.
// c_mode=1: store C fp32 when world is fp32 (probe via hs_probe).
// ---------------------------------------------------------------------------
__global__ __launch_bounds__(256) void gemm128(const unsigned short* __restrict__ A,
                                               const unsigned short* __restrict__ B0,
                                               const unsigned short* __restrict__ B1,
                                               const unsigned short* __restrict__ B2,
                                               void* __restrict__ C,
                                               int M, int N, int K,
                                               int nb1, int nb2,
                                               const unsigned short* __restrict__ hs_probe,
                                               int c_mode) {
    __shared__ unsigned short As[128 * 32];
    __shared__ unsigned short Bs[128 * 32];
    int tid = threadIdx.x;
    int wave = tid >> 6, lane = tid & 63;
    int quad = lane >> 4, l16 = lane & 15;
    int bn_t = blockIdx.x;
    int bm = blockIdx.y * 128, bn = bn_t * 128;

    const unsigned short* Bseg;
    int brow0;
    if (bn_t < nb1)      { Bseg = B0; brow0 = bn; }
    else if (bn_t < nb2) { Bseg = B1; brow0 = bn - nb1 * 128; }
    else                 { Bseg = B2; brow0 = bn - nb2 * 128; }

    int srow = tid >> 2;
    int slot = tid & 3;
    int wm = (wave >> 1) * 64, wn = (wave & 1) * 64;

    floatx4 acc[4][4] = {};

    for (int k0 = 0; k0 < K; k0 += 32) {
#pragma unroll
        for (int half = 0; half < 2; half++) {
            int r = srow + half * 64;
            int gc = slot ^ ((r >> 1) & 3);
            const unsigned short* ga = A + (size_t)(bm + r) * K + k0 + gc * 8;
            __builtin_amdgcn_global_load_lds(
                (const __attribute__((address_space(1))) unsigned int*)ga,
                (__attribute__((address_space(3))) unsigned int*)&As[r * 32 + slot * 8],
                16, 0, 0);
            const unsigned short* gb = Bseg + (size_t)(brow0 + r) * K + k0 + gc * 8;
            __builtin_amdgcn_global_load_lds(
                (const __attribute__((address_space(1))) unsigned int*)gb,
                (__attribute__((address_space(3))) unsigned int*)&Bs[r * 32 + slot * 8],
                16, 0, 0);
        }
        __syncthreads();
        short8 af[4], bf[4];
#pragma unroll
        for (int mt = 0; mt < 4; mt++) {
            int r = wm + mt * 16 + l16;
            af[mt] = *(const short8*)&As[r * 32 + (quad ^ ((r >> 1) & 3)) * 8];
        }
#pragma unroll
        for (int nt = 0; nt < 4; nt++) {
            int r = wn + nt * 16 + l16;
            bf[nt] = *(const short8*)&Bs[r * 32 + (quad ^ ((r >> 1) & 3)) * 8];
        }
#pragma unroll
        for (int mt = 0; mt < 4; mt++)
#pragma unroll
            for (int nt = 0; nt < 4; nt++)
                acc[mt][nt] = __builtin_amdgcn_mfma_f32_16x16x32_bf16(af[mt], bf[nt], acc[mt][nt], 0, 0, 0);
        __syncthreads();
    }

    int cf32 = c_mode ? !world_is_bf16(hs_probe) : 0;
    // C/D layout: col = lane&15, row = quad*4 + reg  [m89/m91 verified]
#pragma unroll
    for (int mt = 0; mt < 4; mt++)
#pragma unroll
        for (int nt = 0; nt < 4; nt++)
#pragma unroll
            for (int r = 0; r < 4; r++) {
                int row = bm + wm + mt * 16 + quad * 4 + r;
                int col = bn + wn + nt * 16 + l16;
                size_t idx = (size_t)row * N + col;
                if (cf32) ((float*)C)[idx] = acc[mt][nt][r];
                else      ((unsigned short*)C)[idx] = f_to_bf16(acc[mt][nt][r]);
            }
}

// ---------------------------------------------------------------------------
// Kernel 3: RoPE in place on fused qkv [BL][3072].
// ---------------------------------------------------------------------------
__global__ __launch_bounds__(256) void rope_kernel(unsigned short* __restrict__ qkv,
                                                   const int* __restrict__ pos_ids) {
    int stride = pid_stride(pos_ids);
    int idx = blockIdx.x * 256 + threadIdx.x;
    int i = idx & 63;
    int tmp = idx >> 6;
    int head = tmp % 20;
    int bl = tmp / 20;
    if (bl >= B_ * L_) return;
    float posf = (float)pos_ids[bl * stride];
    float inv = exp2f(-(float)i * (2.0f / 128.0f) * 13.287712379549449f);
    float ang = posf * inv;
    float c = cosf(ang), sn = sinf(ang);
    unsigned short* p = qkv + (size_t)bl * QKV_N +
                        ((head < H_) ? head * D_ : 2048 + (head - H_) * D_);
    float x0 = bf16_to_f(p[i]), x1 = bf16_to_f(p[i + 64]);
    p[i]      = f_to_bf16(x0 * c - x1 * sn);
    p[i + 64] = f_to_bf16(x1 * c + x0 * sn);
}

// ---------------------------------------------------------------------------
// Kernel 4: MFMA flash attention (unchanged from R7/R8 — verified fast).
// ---------------------------------------------------------------------------
__global__ __launch_bounds__(256, 4) void attn_mfma(const unsigned short* __restrict__ qkv,
                                                    const int* __restrict__ counts,
                                                    const int* __restrict__ poslist,
                                                    unsigned short* __restrict__ o) {
    int qt  = blockIdx.x & 127;
    int kvh = (blockIdx.x >> 7) & 3;
    int s   = (blockIdx.x >> 9) & 7;
    int b   = blockIdx.x >> 12;
    int n = counts[b * NS_ + s];
    if (qt * 16 >= n) return;
    const int* plist = poslist + ((size_t)b * NS_ + s) * L_;

    __shared__ short Ksh[32][136];
    __shared__ short Vsh[128][40];
    __shared__ short Psh[4][16][40];
    __shared__ int posq[16];

    int tid = threadIdx.x;
    int wave = tid >> 6, lane = tid & 63;
    int quad = lane >> 4, l16 = lane & 15;
    int h = kvh * 4 + wave;
    const float scale = 0.08838834764831845f;

    if (tid < 16) posq[tid] = plist[min(qt * 16 + tid, n - 1)];
    __syncthreads();

    short8 qf[4];
    {
        const unsigned short* gq =
            qkv + ((size_t)(b << 11) + posq[l16]) * QKV_N + h * D_;
#pragma unroll
        for (int kk = 0; kk < 4; kk++)
            qf[kk] = *(const short8*)(gq + kk * 32 + quad * 8);
    }

    float m_r[4], l_r[4];
    floatx4 Ov[8];
#pragma unroll
    for (int r4 = 0; r4 < 4; r4++) { m_r[r4] = -1e30f; l_r[r4] = 0.f; }
#pragma unroll
    for (int nt = 0; nt < 8; nt++) Ov[nt] = (floatx4){0.f, 0.f, 0.f, 0.f};

    int c0 = max(0, (qt * 16 - WIN_) >> 5);
    int nch = ((qt * 16 + 15) >> 5) + 1;

    int r = tid >> 3, seg = tid & 7;
    int vc = r ^ ((seg & 3) << 3);
    short8 kr0, kr1, vr0, vr1;
    {
        int kpos = plist[min(c0 * 32 + r, n - 1)];
        size_t base = ((size_t)(b << 11) + kpos) * QKV_N + 2048 + kvh * D_ + seg * 16;
        kr0 = *(const short8*)(qkv + base);
        kr1 = *(const short8*)(qkv + base + 8);
        vr0 = *(const short8*)(qkv + base + 512);
        vr1 = *(const short8*)(qkv + base + 520);
    }

    for (int c = c0; c < nch; c++) {
        *(short8*)&Ksh[r][seg * 16]     = kr0;
        *(short8*)&Ksh[r][seg * 16 + 8] = kr1;
#pragma unroll
        for (int e = 0; e < 8; e++) Vsh[seg * 16 + e][vc] = vr0[e];
#pragma unroll
        for (int e = 0; e < 8; e++) Vsh[seg * 16 + 8 + e][vc] = vr1[e];
        __syncthreads();

        if (c + 1 < nch) {
            int kpos = plist[min((c + 1) * 32 + r, n - 1)];
            size_t base = ((size_t)(b << 11) + kpos) * QKV_N + 2048 + kvh * D_ + seg * 16;
            kr0 = *(const short8*)(qkv + base);
            kr1 = *(const short8*)(qkv + base + 8);
            vr0 = *(const short8*)(qkv + base + 512);
            vr1 = *(const short8*)(qkv + base + 520);
        }

        floatx4 s0 = (floatx4){0.f, 0.f, 0.f, 0.f};
        floatx4 s1 = (floatx4){0.f, 0.f, 0.f, 0.f};
#pragma unroll
        for (int kk = 0; kk < 4; kk++) {
            short8 kfa = *(const short8*)&Ksh[l16][kk * 32 + quad * 8];
            s0 = __builtin_amdgcn_mfma_f32_16x16x32_bf16(qf[kk], kfa, s0, 0, 0, 0);
        }
#pragma unroll
        for (int kk = 0; kk < 4; kk++) {
            short8 kfb = *(const short8*)&Ksh[16 + l16][kk * 32 + quad * 8];
            s1 = __builtin_amdgcn_mfma_f32_16x16x32_bf16(qf[kk], kfb, s1, 0, 0, 0);
        }

        int kr0i = c * 32 + l16, kr1i = kr0i + 16;
        float x0[4], x1[4], rmax[4];
#pragma unroll
        for (int r4 = 0; r4 < 4; r4++) {
            int qr = qt * 16 + quad * 4 + r4;
            bool mk0 = (kr0i <= qr) && (kr0i >= qr - WIN_);
            bool mk1 = (kr1i <= qr) && (kr1i >= qr - WIN_);
            x0[r4] = mk0 ? s0[r4] * scale : -1e30f;
            x1[r4] = mk1 ? s1[r4] * scale : -1e30f;
            rmax[r4] = fmaxf(x0[r4], x1[r4]);
        }
#pragma unroll
        for (int st = 1; st <= 8; st <<= 1)
#pragma unroll
            for (int r4 = 0; r4 < 4; r4++)
                rmax[r4] = fmaxf(rmax[r4], __shfl_xor(rmax[r4], st, 64));
        float al[4], psum[4];
#pragma unroll
        for (int r4 = 0; r4 < 4; r4++) {
            float nm = fmaxf(m_r[r4], rmax[r4]);
            al[r4] = __expf(m_r[r4] - nm);
            m_r[r4] = nm;
            x0[r4] = (x0[r4] > -1e29f) ? __expf(x0[r4] - nm) : 0.f;
            x1[r4] = (x1[r4] > -1e29f) ? __expf(x1[r4] - nm) : 0.f;
            psum[r4] = x0[r4] + x1[r4];
        }
#pragma unroll
        for (int st = 1; st <= 8; st <<= 1)
#pragma unroll
            for (int r4 = 0; r4 < 4; r4++)
                psum[r4] += __shfl_xor(psum[r4], st, 64);
#pragma unroll
        for (int r4 = 0; r4 < 4; r4++) l_r[r4] = l_r[r4] * al[r4] + psum[r4];
#pragma unroll
        for (int nt = 0; nt < 8; nt++)
#pragma unroll
            for (int r4 = 0; r4 < 4; r4++) Ov[nt][r4] *= al[r4];

#pragma unroll
        for (int r4 = 0; r4 < 4; r4++) {
            Psh[wave][quad * 4 + r4][l16]      = (short)f_to_bf16(x0[r4]);
            Psh[wave][quad * 4 + r4][16 + l16] = (short)f_to_bf16(x1[r4]);
        }
        short8 pf = *(const short8*)&Psh[wave][l16][quad * 8];

#pragma unroll
        for (int nt = 0; nt < 8; nt++) {
            short8 vf = *(const short8*)&Vsh[nt * 16 + l16][(quad ^ (nt & 3)) * 8];
            Ov[nt] = __builtin_amdgcn_mfma_f32_16x16x32_bf16(pf, vf, Ov[nt], 0, 0, 0);
        }
        __syncthreads();
    }

    float inv_r[4];
    int pos_r[4], qvalid[4];
#pragma unroll
    for (int r4 = 0; r4 < 4; r4++) {
        int qr = qt * 16 + quad * 4 + r4;
        qvalid[r4] = (qr < n);
        inv_r[r4] = 1.f / l_r[r4];
        pos_r[r4] = posq[quad * 4 + r4];
    }
#pragma unroll
    for (int nt = 0; nt < 8; nt++)
#pragma unroll
        for (int r4 = 0; r4 < 4; r4++)
            if (qvalid[r4])
                o[(((size_t)(b << 11) + pos_r[r4]) * H_ + h) * D_ + nt * 16 + l16] =
                    f_to_bf16(Ov[nt][r4] * inv_r[r4]);
}

// ---------------------------------------------------------------------------
extern "C" void kernel_launch(void* const* d_in, const int* in_sizes, int n_in,
                              void* d_out, int out_size, void* d_ws, size_t ws_size,
                              hipStream_t stream) {
    const void* hs = d_in[0];
    const void* Wq = d_in[1];
    const void* Wk = d_in[2];
    const void* Wv = d_in[3];
    const void* Wo = d_in[4];
    const int* sid  = (const int*)d_in[5];
    const int* pids = (const int*)d_in[6];

    const int M = B_ * L_;  // 4096
    char* w = (char*)d_ws;
    unsigned short* qkv  = (unsigned short*)(w + 256);          // 25,165,824
    unsigned short* o_b  = (unsigned short*)(w + 25166080);     // 16,777,216
    unsigned short* c_hs = (unsigned short*)(w + 41943296);     // 16,777,216
    unsigned short* c_Wq = (unsigned short*)(w + 58720512);     //  8,388,608
    unsigned short* c_Wk = (unsigned short*)(w + 67109120);     //  2,097,152
    unsigned short* c_Wv = (unsigned short*)(w + 69206272);     //  2,097,152
    unsigned short* c_Wo = (unsigned short*)(w + 71303424);     //  8,388,608
    int* rank            = (int*)(w + 79692032);                //     16,384
    int* plist           = (int*)(w + 79708416);                //    131,072
    int* counts          = (int*)(w + 79839488);                //        256

    const unsigned short* hs_probe = (const unsigned short*)hs;

    // 1 launch: all dtype canonicalization
    convert_all<<<2048, 256, 0, stream>>>(hs, Wq, Wk, Wv, Wo,
                                          c_hs, c_Wq, c_Wk, c_Wv, c_Wo);

    scan_kernel<<<B_, 256, 0, stream>>>(sid, pids, rank, plist, counts);

    // fused QKV projection: N = 3072, tiles [0,16)=Wq, [16,20)=Wk, [20,24)=Wv
    gemm128<<<dim3(QKV_N / 128, M / 128), 256, 0, stream>>>(
        c_hs, c_Wq, c_Wk, c_Wv, qkv, M, QKV_N, HID_, 16, 20, hs_probe, 0);

    int rope_threads = M * (H_ + KVH_) * 64;
    rope_kernel<<<(rope_threads + 255) / 256, 256, 0, stream>>>(qkv, pids);

    attn_mfma<<<B_ * NS_ * KVH_ * (L_ / 16), 256, 0, stream>>>(qkv, counts, plist, o_b);

    gemm128<<<dim3(HID_ / 128, M / 128), 256, 0, stream>>>(
        o_b, c_Wo, c_Wo, c_Wo, d_out, M, HID_, HID_, 1 << 30, 1 << 30, hs_probe, 1);
}